// Round 1
// baseline (972.042 us; speedup 1.0000x reference)
//
#include <hip/hip_runtime.h>
#include <math.h>

#define TT 256   // seq len
#define DD 512   // d_model
#define NN 8     // heads
#define HH 64    // head dim

// workspace layout in floats
#define PROJ_SZ (NN*TT*HH)          // 131072 per projection
#define OFF_K1 0
#define OFF_K2 (1*PROJ_SZ)
#define OFF_Q  (2*PROJ_SZ)
#define OFF_V1 (3*PROJ_SZ)
#define OFF_V2 (4*PROJ_SZ)
#define OFF_STEP1 (5*PROJ_SZ)
#define STEP1_SZ (NN*TT*HH*HH)      // 8388608
#define OFF_A (OFF_STEP1 + STEP1_SZ)
#define A_SZ (NN*TT*HH*HH)
#define OFF_Z (OFF_A + A_SZ)        // NN*TT*HH

// ---------------- projections: out[n][t][h] = sum_d x[t][d]*W[n][d][h] + b[n][h]
__global__ void proj_kernel(const float* __restrict__ x,
                            const float* __restrict__ W,
                            const float* __restrict__ bias,
                            float* __restrict__ out) {
    int n = blockIdx.x;                 // 0..7
    int tl = threadIdx.x >> 6;          // 0..3
    int h = threadIdx.x & 63;
    int t = blockIdx.y * 4 + tl;        // 0..255
    const float* xrow = x + t * DD;
    const float* Wn = W + (size_t)n * DD * HH + h;
    float acc = 0.f;
    for (int d = 0; d < DD; ++d) acc += xrow[d] * Wn[(size_t)d * HH];
    out[((size_t)n * TT + t) * HH + h] = acc + bias[n * HH + h];
}

// ---------------- step1[n][r][i][j] = sum_k q[n][r][k] * W_Kq[n][i][j][k]
__global__ void step1_kernel(const float* __restrict__ q,
                             const float* __restrict__ W_Kq,
                             float* __restrict__ step1) {
    int n = blockIdx.x, i = blockIdx.y;
    int r = threadIdx.x;                // 0..255
    __shared__ float sw[HH * HH];       // W_Kq[n][i][j][k], 16KB
    const float* wsrc = W_Kq + (((size_t)n * HH + i) * HH) * HH;
    for (int m = 0; m < 16; ++m) sw[m * 256 + threadIdx.x] = wsrc[m * 256 + threadIdx.x];
    __syncthreads();
    float acc[HH];
    #pragma unroll
    for (int j = 0; j < HH; ++j) acc[j] = 0.f;
    const float* qrow = q + ((size_t)n * TT + r) * HH;
    for (int k = 0; k < HH; ++k) {
        float qv = qrow[k];
        #pragma unroll
        for (int j = 0; j < HH; ++j) acc[j] += sw[j * HH + k] * qv;
    }
    float* dst = step1 + (((size_t)n * TT + r) * HH + i) * HH;
    #pragma unroll
    for (int j = 0; j < HH; ++j) dst[j] = acc[j];
}

// ---------------- A[n][t][i][h] = sum_j v2[n][t][j] * W_Vq[n][i][j][h]
__global__ void amat_kernel(const float* __restrict__ v2,
                            const float* __restrict__ W_Vq,
                            float* __restrict__ A) {
    int n = blockIdx.x, i = blockIdx.y;
    int t = threadIdx.x;
    __shared__ float sw[HH * HH];       // W_Vq[n][i][j][h]
    const float* wsrc = W_Vq + (((size_t)n * HH + i) * HH) * HH;
    for (int m = 0; m < 16; ++m) sw[m * 256 + threadIdx.x] = wsrc[m * 256 + threadIdx.x];
    __syncthreads();
    float acc[HH];
    #pragma unroll
    for (int h = 0; h < HH; ++h) acc[h] = 0.f;
    const float* vrow = v2 + ((size_t)n * TT + t) * HH;
    for (int j = 0; j < HH; ++j) {
        float vv = vrow[j];
        #pragma unroll
        for (int h = 0; h < HH; ++h) acc[h] += sw[j * HH + h] * vv;
    }
    float* dst = A + (((size_t)n * TT + t) * HH + i) * HH;
    #pragma unroll
    for (int h = 0; h < HH; ++h) dst[h] = acc[h];
}

// ---------------- main attention kernel: one block per (r, n)
__global__ __launch_bounds__(256) void attn_kernel(
    const float* __restrict__ k1, const float* __restrict__ k2,
    const float* __restrict__ v1, const float* __restrict__ step1,
    const float* __restrict__ A, float* __restrict__ z)
{
    int r = blockIdx.x;   // 0..255
    int n = blockIdx.y;   // 0..7
    int tid = threadIdx.x;
    int t_local = tid >> 1;
    int half = tid & 1;

    if (r < 2) {  // no valid (s,t) pairs: softmax lands on dummy slot -> z = 0
        if (tid < HH) z[((size_t)n * TT + r) * HH + tid] = 0.f;
        return;
    }

    __shared__ float lds_a[128 * 64];   // 32KB: step1 during phase a, W during phase c
    __shared__ float s_k1[32 * 64];     // 8KB
    __shared__ float s_v1[32 * 64];     // 8KB

    const float* step1_src = step1 + (((size_t)n * TT + r) * HH) * HH;

    float num_part = 0.f;   // partial for (grp = tid>>6, h = tid&63)
    float den_part = 0.f;   // only half==0 threads accumulate

    int nchunks = (r > 128) ? 2 : 1;
    for (int c = 0; c < nchunks; ++c) {
        int t0 = c * 128;
        __syncthreads();   // protect lds_a from previous chunk's phase-2 reads
        for (int m = 0; m < 16; ++m) lds_a[m * 256 + tid] = step1_src[m * 256 + tid];
        __syncthreads();

        int t = t0 + t_local;
        bool active = (t >= 1) && (t < r);

        // ---- phase a: g[i'] = sum_j step1[half*32+i'][j] * k2[t][j]
        float4 g4[8];
        #pragma unroll
        for (int m = 0; m < 8; ++m) g4[m] = make_float4(0.f, 0.f, 0.f, 0.f);
        if (active) {
            const float* k2row = k2 + ((size_t)n * TT + t) * HH;
            for (int j4 = 0; j4 < 16; ++j4) {
                float4 kv = *(const float4*)(k2row + j4 * 4);
                #pragma unroll
                for (int m = 0; m < 8; ++m) {
                    const float* sp = &lds_a[(half * 32 + m * 4) * 64 + j4 * 4];
                    float4 r0 = *(const float4*)(sp);
                    float4 r1 = *(const float4*)(sp + 64);
                    float4 r2 = *(const float4*)(sp + 128);
                    float4 r3 = *(const float4*)(sp + 192);
                    g4[m].x += r0.x*kv.x + r0.y*kv.y + r0.z*kv.z + r0.w*kv.w;
                    g4[m].y += r1.x*kv.x + r1.y*kv.y + r1.z*kv.z + r1.w*kv.w;
                    g4[m].z += r2.x*kv.x + r2.y*kv.y + r2.z*kv.z + r2.w*kv.w;
                    g4[m].w += r3.x*kv.x + r3.y*kv.y + r3.z*kv.z + r3.w*kv.w;
                }
            }
        }

        // ---- phase b: loop s tiles; accumulate w[i'] and den
        float4 w4[8];
        #pragma unroll
        for (int m = 0; m < 8; ++m) w4[m] = make_float4(0.f, 0.f, 0.f, 0.f);
        int tmax = min(t0 + 128, r);       // exclusive bound on t in this chunk
        int smax_excl = tmax - 1;          // s < t <= tmax-1  ->  s < tmax-1
        int nsb = (smax_excl + 31) / 32;   // uniform per block
        for (int sb = 0; sb < nsb; ++sb) {
            __syncthreads();
            for (int m = 0; m < 8; ++m) {
                int idx = m * 256 + tid;
                int sr = idx >> 6, col = idx & 63;
                s_k1[idx] = k1[((size_t)n * TT + sb * 32 + sr) * HH + col];
                s_v1[idx] = v1[((size_t)n * TT + sb * 32 + sr) * HH + col];
            }
            __syncthreads();
            if (active) {
                int s_hi = t - sb * 32;
                if (s_hi > 32) s_hi = 32;
                for (int ss = 0; ss < s_hi; ++ss) {
                    float l = 0.f;
                    const float* kr = &s_k1[ss * 64 + half * 32];
                    #pragma unroll
                    for (int m = 0; m < 8; ++m) {
                        float4 a4 = *(const float4*)(kr + m * 4);
                        l += a4.x*g4[m].x + a4.y*g4[m].y + a4.z*g4[m].z + a4.w*g4[m].w;
                    }
                    l += __shfl_xor(l, 1);
                    float e = __expf(l * 0.015625f);   // /64 scale
                    if (half == 0) den_part += e;
                    const float* vr = &s_v1[ss * 64 + half * 32];
                    #pragma unroll
                    for (int m = 0; m < 8; ++m) {
                        float4 a4 = *(const float4*)(vr + m * 4);
                        w4[m].x += e * a4.x; w4[m].y += e * a4.y;
                        w4[m].z += e * a4.z; w4[m].w += e * a4.w;
                    }
                }
            }
        }

        // ---- phase c: write W into lds_a, then contract with A
        __syncthreads();
        float* wrow = &lds_a[t_local * 64 + half * 32];
        #pragma unroll
        for (int m = 0; m < 8; ++m) *(float4*)(wrow + m * 4) = w4[m];
        __syncthreads();

        int grp = tid >> 6, h = tid & 63;
        int tl_lo = grp * 32;
        int tl_hi = min(grp * 32 + 32, tmax - t0);
        for (int tl = tl_lo; tl < tl_hi; ++tl) {
            int tg = t0 + tl;
            const float* arow = A + (((size_t)n * TT + tg) * HH) * HH + h;
            #pragma unroll 8
            for (int i = 0; i < HH; ++i) {
                num_part += lds_a[tl * 64 + i] * arow[(size_t)i * HH];
            }
        }
    }

    // ---- final reductions (reuse s_k1 / s_v1)
    __syncthreads();
    s_k1[tid] = den_part;
    s_v1[tid] = num_part;
    __syncthreads();
    if (tid < HH) {
        float den = 0.f;
        for (int m = 0; m < 256; ++m) den += s_k1[m];
        float num = s_v1[tid] + s_v1[64 + tid] + s_v1[128 + tid] + s_v1[192 + tid];
        float zv = (den > 0.f) ? (num / den) : 0.f;
        z[((size_t)n * TT + r) * HH + tid] = zv;
    }
}

// ---------------- out[t][d] = b_O[d] + sum_{n,h} z[n][t][h] * W_O[n][h][d]
__global__ void out_kernel(const float* __restrict__ z, const float* __restrict__ W_O,
                           const float* __restrict__ b_O, float* __restrict__ out) {
    int t = blockIdx.x;
    int tid = threadIdx.x;
    __shared__ float sz[NN * HH];   // 512 floats
    for (int m = 0; m < 2; ++m) {
        int idx = m * 256 + tid;    // idx = n*64 + h
        int n = idx >> 6, h = idx & 63;
        sz[idx] = z[((size_t)n * TT + t) * HH + h];
    }
    __syncthreads();
    for (int m = 0; m < 2; ++m) {
        int d = m * 256 + tid;
        float acc = b_O[d];
        for (int qq = 0; qq < NN * HH; ++qq) {
            acc += sz[qq] * W_O[(size_t)qq * DD + d];
        }
        out[(size_t)t * DD + d] = acc;
    }
}

extern "C" void kernel_launch(void* const* d_in, const int* in_sizes, int n_in,
                              void* d_out, int out_size, void* d_ws, size_t ws_size,
                              hipStream_t stream) {
    const float* x    = (const float*)d_in[0];
    const float* W_K1 = (const float*)d_in[1];
    const float* W_K2 = (const float*)d_in[2];
    const float* W_Q  = (const float*)d_in[3];
    const float* W_V1 = (const float*)d_in[4];
    const float* W_V2 = (const float*)d_in[5];
    const float* W_Kq = (const float*)d_in[6];
    const float* W_Vq = (const float*)d_in[7];
    const float* W_O  = (const float*)d_in[8];
    const float* b_K1 = (const float*)d_in[9];
    const float* b_K2 = (const float*)d_in[10];
    const float* b_Q  = (const float*)d_in[11];
    const float* b_V1 = (const float*)d_in[12];
    const float* b_V2 = (const float*)d_in[13];
    const float* b_O  = (const float*)d_in[14];
    float* ws = (float*)d_ws;
    float* out = (float*)d_out;

    dim3 pg(NN, TT / 4);
    proj_kernel<<<pg, 256, 0, stream>>>(x, W_K1, b_K1, ws + OFF_K1);
    proj_kernel<<<pg, 256, 0, stream>>>(x, W_K2, b_K2, ws + OFF_K2);
    proj_kernel<<<pg, 256, 0, stream>>>(x, W_Q,  b_Q,  ws + OFF_Q);
    proj_kernel<<<pg, 256, 0, stream>>>(x, W_V1, b_V1, ws + OFF_V1);
    proj_kernel<<<pg, 256, 0, stream>>>(x, W_V2, b_V2, ws + OFF_V2);

    step1_kernel<<<dim3(NN, HH), 256, 0, stream>>>(ws + OFF_Q,  W_Kq, ws + OFF_STEP1);
    amat_kernel <<<dim3(NN, HH), 256, 0, stream>>>(ws + OFF_V2, W_Vq, ws + OFF_A);

    attn_kernel<<<dim3(TT, NN), 256, 0, stream>>>(ws + OFF_K1, ws + OFF_K2, ws + OFF_V1,
                                                  ws + OFF_STEP1, ws + OFF_A, ws + OFF_Z);

    out_kernel<<<TT, 256, 0, stream>>>(ws + OFF_Z, W_O, b_O, out);
}

// Round 2
// 328.932 us; speedup vs baseline: 2.9552x; 2.9552x over previous
//
#include <hip/hip_runtime.h>
#include <hip/hip_bf16.h>
#include <math.h>

#define TT 256   // seq len
#define DD 512   // d_model
#define NN 8     // heads
#define HH 64    // head dim

typedef __attribute__((ext_vector_type(8))) short short8v;   // 8 bf16 (4 VGPR)
typedef __attribute__((ext_vector_type(4))) short short4v;   // 4 bf16 (2 VGPR)
typedef __attribute__((ext_vector_type(4))) float f32x4;

__device__ __forceinline__ short f2bf(float x) {
    union { float f; unsigned u; } v; v.f = x;
    unsigned r = (v.u + 0x7FFFu + ((v.u >> 16) & 1u)) >> 16;   // RNE
    return (short)r;
}

// ---------------- workspace layout ----------------
// float region (in floats)
#define F_K1   0
#define F_K2   131072
#define F_Q    262144
#define F_V1   393216
#define F_V2   524288
#define F_A    655360            // 8388608 floats: A[n][t][i][h] fp32
#define F_NUM  9043968           // 131072
#define F_DEN  9175040           // 2048
#define F_Z    9177088           // 131072
#define F_TOTAL 9308160          // floats (= 37,232,640 B, 16B aligned)
// short (bf16) region, base = (short*)(ws + F_TOTAL), offsets in shorts
#define S_K1B  0
#define S_K2B  131072
#define S_V1B  262144
#define S_S1B  393216            // 8388608: step1 bf16 [n][r][i][j]
#define S_AB   8781824           // 8388608: Ab [n][t][h][i]
#define S_GB   17170432          // 33554432: G [n][r][t][i]
#define S_UB   50724864          // 33554432: U [n][t][s][h]
// grand total ~206 MB of d_ws

// ---------------- projections: out[n][t][h] = sum_d x[t][d]*W[n][d][h] + b ----
__global__ void proj_kernel(const float* __restrict__ x,
                            const float* __restrict__ W,
                            const float* __restrict__ bias,
                            float* __restrict__ out,
                            short* __restrict__ outb) {
    int n = blockIdx.x;
    int tl = threadIdx.x >> 6;
    int h = threadIdx.x & 63;
    int t = blockIdx.y * 4 + tl;
    const float* xrow = x + t * DD;
    const float* Wn = W + (size_t)n * DD * HH + h;
    float acc = 0.f;
    for (int d = 0; d < DD; ++d) acc += xrow[d] * Wn[(size_t)d * HH];
    float r = acc + bias[n * HH + h];
    size_t idx = ((size_t)n * TT + t) * HH + h;
    out[idx] = r;
    if (outb) outb[idx] = f2bf(r);
}

// ---------- step1[n][r][i][j] = sum_k q[n][r][k]*W_Kq[n][i][j][k]  (bf16 out) --
__global__ void step1_kernel(const float* __restrict__ q,
                             const float* __restrict__ W_Kq,
                             short* __restrict__ S1b) {
    int n = blockIdx.x, i = blockIdx.y;
    int rr = threadIdx.x;
    __shared__ float sw[HH * HH];
    const float* wsrc = W_Kq + (((size_t)n * HH + i) * HH) * HH;
    for (int m = 0; m < 16; ++m) sw[m * 256 + threadIdx.x] = wsrc[m * 256 + threadIdx.x];
    __syncthreads();
    float acc[HH];
    #pragma unroll
    for (int j = 0; j < HH; ++j) acc[j] = 0.f;
    const float* qrow = q + ((size_t)n * TT + rr) * HH;
    for (int k = 0; k < HH; ++k) {
        float qv = qrow[k];
        #pragma unroll
        for (int j = 0; j < HH; ++j) acc[j] += sw[j * HH + k] * qv;
    }
    short* dst = S1b + (((size_t)n * TT + rr) * HH + i) * HH;
    #pragma unroll
    for (int jj = 0; jj < 8; ++jj) {
        short8v o;
        #pragma unroll
        for (int e = 0; e < 8; ++e) o[e] = f2bf(acc[jj * 8 + e]);
        *(short8v*)(dst + jj * 8) = o;
    }
}

// ---------- A[n][t][i][h] = sum_j v2[n][t][j]*W_Vq[n][i][j][h]  (fp32) --------
__global__ void amat_kernel(const float* __restrict__ v2,
                            const float* __restrict__ W_Vq,
                            float* __restrict__ A) {
    int n = blockIdx.x, i = blockIdx.y;
    int t = threadIdx.x;
    __shared__ float sw[HH * HH];
    const float* wsrc = W_Vq + (((size_t)n * HH + i) * HH) * HH;
    for (int m = 0; m < 16; ++m) sw[m * 256 + threadIdx.x] = wsrc[m * 256 + threadIdx.x];
    __syncthreads();
    float acc[HH];
    #pragma unroll
    for (int h = 0; h < HH; ++h) acc[h] = 0.f;
    const float* vrow = v2 + ((size_t)n * TT + t) * HH;
    for (int j = 0; j < HH; ++j) {
        float vv = vrow[j];
        #pragma unroll
        for (int h = 0; h < HH; ++h) acc[h] += sw[j * HH + h] * vv;
    }
    float* dst = A + (((size_t)n * TT + t) * HH + i) * HH;
    #pragma unroll
    for (int h = 0; h < HH; ++h) dst[h] = acc[h];
}

// ---------- Ab[n][t][h][i] = bf16(A[n][t][i][h])  (transpose-convert) ---------
__global__ void trA_kernel(const float* __restrict__ A, short* __restrict__ Ab) {
    int nt = blockIdx.x;                 // n*256+t
    __shared__ float lds[64 * 65];
    const float* src = A + (size_t)nt * 4096;
    for (int p = 0; p < 16; ++p) {
        int m = p * 256 + threadIdx.x;
        int i = m >> 6, h = m & 63;
        lds[i * 65 + h] = src[m];
    }
    __syncthreads();
    int h = threadIdx.x >> 2, i0 = (threadIdx.x & 3) * 16;
    short* dst = Ab + (size_t)nt * 4096 + h * 64 + i0;
    short8v o0, o1;
    #pragma unroll
    for (int e = 0; e < 8; ++e) o0[e] = f2bf(lds[(i0 + e) * 65 + h]);
    #pragma unroll
    for (int e = 0; e < 8; ++e) o1[e] = f2bf(lds[(i0 + 8 + e) * 65 + h]);
    *(short8v*)dst = o0;
    *(short8v*)(dst + 8) = o1;
}

// ---------- G[n][r][t][i] = sum_j S1[n][r][i][j]*k2[n][t][j]  (MFMA) ----------
// GEMM per head: C(m=(r,i), t) = S1flat(m, j) * K2^T(j, t)
__global__ __launch_bounds__(256) void gmat_kernel(const short* __restrict__ S1b,
                                                   const short* __restrict__ K2b,
                                                   short* __restrict__ G) {
    int n = blockIdx.y;
    int wave = threadIdx.x >> 6, lane = threadIdx.x & 63;
    int g = lane >> 4, c = lane & 15;
    int mt = blockIdx.x * 4 + wave;          // m-tile 0..1023
    int r = mt >> 2, i0 = (mt & 3) * 16;
    __shared__ short tl[4][16 * 17];
    short* my = tl[wave];
    const short* abase = S1b + ((size_t)n * 16384 + mt * 16 + c) * 64 + g * 8;
    short8v a0 = *(const short8v*)abase;
    short8v a1 = *(const short8v*)(abase + 32);
    for (int tt = 0; tt < 16; ++tt) {
        const short* bbase = K2b + ((size_t)n * TT + tt * 16 + c) * 64 + g * 8;
        short8v b0 = *(const short8v*)bbase;
        short8v b1 = *(const short8v*)(bbase + 32);
        f32x4 acc = {0.f, 0.f, 0.f, 0.f};
        acc = __builtin_amdgcn_mfma_f32_16x16x32_bf16(a0, b0, acc, 0, 0, 0);
        acc = __builtin_amdgcn_mfma_f32_16x16x32_bf16(a1, b1, acc, 0, 0, 0);
        __syncthreads();
        #pragma unroll
        for (int m = 0; m < 4; ++m) my[c * 17 + g * 4 + m] = f2bf(acc[m]);
        __syncthreads();
        int trow = lane >> 2, qq = (lane & 3) * 4;
        short4v ov;
        #pragma unroll
        for (int e = 0; e < 4; ++e) ov[e] = my[trow * 17 + qq + e];
        *(short4v*)(&G[(((size_t)(n * TT + r) * TT) + tt * 16 + trow) * 64 + i0 + qq]) = ov;
    }
}

// ---------- U[n][t][s][h] = sum_i v1[n][s][i]*A[n][t][i][h]  (MFMA) -----------
__global__ __launch_bounds__(256) void umat_kernel(const short* __restrict__ V1b,
                                                   const short* __restrict__ Ab,
                                                   short* __restrict__ U) {
    int n = blockIdx.y, t = blockIdx.x;
    int wave = threadIdx.x >> 6, lane = threadIdx.x & 63;
    int g = lane >> 4, c = lane & 15;
    __shared__ short tl[4][16 * 17];
    short* my = tl[wave];
    for (int it = 0; it < 4; ++it) {
        int mt = it * 4 + wave;              // s-tile 0..15
        const short* abase = V1b + ((size_t)n * TT + mt * 16 + c) * 64 + g * 8;
        short8v a0 = *(const short8v*)abase;
        short8v a1 = *(const short8v*)(abase + 32);
        for (int ht = 0; ht < 4; ++ht) {
            const short* bbase = Ab + (((size_t)(n * TT + t) * 64) + ht * 16 + c) * 64 + g * 8;
            short8v b0 = *(const short8v*)bbase;
            short8v b1 = *(const short8v*)(bbase + 32);
            f32x4 acc = {0.f, 0.f, 0.f, 0.f};
            acc = __builtin_amdgcn_mfma_f32_16x16x32_bf16(a0, b0, acc, 0, 0, 0);
            acc = __builtin_amdgcn_mfma_f32_16x16x32_bf16(a1, b1, acc, 0, 0, 0);
            __syncthreads();
            #pragma unroll
            for (int m = 0; m < 4; ++m) my[(g * 4 + m) * 17 + c] = f2bf(acc[m]);
            __syncthreads();
            int srow = lane >> 2, qq = (lane & 3) * 4;
            short4v ov;
            #pragma unroll
            for (int e = 0; e < 4; ++e) ov[e] = my[srow * 17 + qq + e];
            *(short4v*)(&U[(((size_t)(n * TT + t) * TT) + mt * 16 + srow) * 64 + ht * 16 + qq]) = ov;
        }
    }
}

// ---------- cubic attention: block = (n, t-tile of 8, s-parity) ---------------
// per t: per s-tile(16): L(s,r^)=K1*G^T (2x mfma 16x16x32), mask+exp,
// num(r^,h) += E^T * U (4x mfma 16x16x16 via transpose trick)
__global__ __launch_bounds__(512) void attn_kernel(
    const short* __restrict__ K1b, const short* __restrict__ Gm,
    const short* __restrict__ Um, float* __restrict__ num, float* __restrict__ den)
{
    int n = blockIdx.y;
    int ttile = blockIdx.x >> 1;
    int sig = blockIdx.x & 1;
    int t0 = ttile * 8;
    int tid = threadIdx.x;
    int wave = tid >> 6, lane = tid & 63, g = lane >> 4, c = lane & 15;

    __shared__ short k1lds[128 * 72];    // [row][64+8pad]
    __shared__ short ulds[128 * 68];     // [row][64+4pad]

    // stage K1 parity s-tiles (st = sig, sig+2, ...; st*16 <= t0+6)
    int stmaxK = (t0 + 6) >> 4;
    int cntK = (stmaxK >= sig) ? ((stmaxK - sig) >> 1) + 1 : 0;
    for (int idx = tid; idx < cntK * 128; idx += 512) {
        int row = idx >> 3, seg = idx & 7;
        int s = (sig + ((row >> 4) << 1)) * 16 + (row & 15);
        short8v v = *(const short8v*)(K1b + ((size_t)n * TT + s) * 64 + seg * 8);
        *(short8v*)(&k1lds[row * 72 + seg * 8]) = v;
    }
    __syncthreads();

    f32x4 numacc[2][4];
    #pragma unroll
    for (int a = 0; a < 2; ++a)
        #pragma unroll
        for (int b = 0; b < 4; ++b) numacc[a][b] = (f32x4){0.f, 0.f, 0.f, 0.f};
    float denacc[2] = {0.f, 0.f};
    int rts0 = wave, rts1 = wave + 8;

    for (int th = 0; th < 8; ++th) {
        int t = t0 + th;
        if (t < 1 || t > 254) continue;
        int rt_start = (t + 1) >> 4;
        int stmaxU = (t - 1) >> 4;
        int cntU = (stmaxU >= sig) ? ((stmaxU - sig) >> 1) + 1 : 0;
        __syncthreads();     // protect previous ulds reads
        for (int idx = tid; idx < cntU * 128; idx += 512) {
            int row = idx >> 3, seg = idx & 7;
            int s = (sig + ((row >> 4) << 1)) * 16 + (row & 15);
            short8v v = *(const short8v*)(Um + (((size_t)(n * TT + t) * TT) + s) * 64 + seg * 8);
            *(short8v*)(&ulds[row * 68 + seg * 8]) = v;
        }
        __syncthreads();
        if (cntU == 0) continue;

        short8v gf0[2], gf1[2];
        bool v0 = (rts0 >= rt_start), v1 = (rts1 >= rt_start);
        if (v0) {
            const short* gb = Gm + (((size_t)(n * TT + rts0 * 16 + c) * TT) + t) * 64 + g * 8;
            gf0[0] = *(const short8v*)gb; gf0[1] = *(const short8v*)(gb + 32);
        }
        if (v1) {
            const short* gb = Gm + (((size_t)(n * TT + rts1 * 16 + c) * TT) + t) * 64 + g * 8;
            gf1[0] = *(const short8v*)gb; gf1[1] = *(const short8v*)(gb + 32);
        }

        for (int loc = 0; loc < cntU; ++loc) {
            int s_base = (sig + loc * 2) * 16;
            short8v af0 = *(const short8v*)(&k1lds[(loc * 16 + c) * 72 + g * 8]);
            short8v af1 = *(const short8v*)(&k1lds[(loc * 16 + c) * 72 + 32 + g * 8]);
            short4v ub[4];
            #pragma unroll
            for (int hs = 0; hs < 4; ++hs) {
                #pragma unroll
                for (int j = 0; j < 4; ++j)
                    ub[hs][j] = ulds[(loc * 16 + g * 4 + j) * 68 + hs * 16 + c];
            }
            #pragma unroll
            for (int a = 0; a < 2; ++a) {
                bool va = a ? v1 : v0;
                if (!va) continue;
                int rt = a ? rts1 : rts0;
                f32x4 lg = {0.f, 0.f, 0.f, 0.f};
                lg = __builtin_amdgcn_mfma_f32_16x16x32_bf16(af0, a ? gf1[0] : gf0[0], lg, 0, 0, 0);
                lg = __builtin_amdgcn_mfma_f32_16x16x32_bf16(af1, a ? gf1[1] : gf0[1], lg, 0, 0, 0);
                int r = rt * 16 + c;
                short4v eb;
                float dsum = 0.f;
                #pragma unroll
                for (int m = 0; m < 4; ++m) {
                    int s = s_base + g * 4 + m;
                    float e = (s < t && r > t) ? __expf(lg[m] * 0.015625f) : 0.f;
                    dsum += e;
                    eb[m] = f2bf(e);
                }
                denacc[a] += dsum;
                #pragma unroll
                for (int hs = 0; hs < 4; ++hs)
                    numacc[a][hs] = __builtin_amdgcn_mfma_f32_16x16x16bf16_1k(eb, ub[hs], numacc[a][hs], 0, 0, 0);
            }
        }
    }

    // epilogue: atomics
    #pragma unroll
    for (int a = 0; a < 2; ++a) {
        int rt = a ? rts1 : rts0;
        if (rt * 16 + 15 <= t0) continue;
        float v = denacc[a];
        v += __shfl_xor(v, 16);
        v += __shfl_xor(v, 32);
        if (lane < 16) atomicAdd(&den[n * TT + rt * 16 + lane], v);
        #pragma unroll
        for (int hs = 0; hs < 4; ++hs)
            #pragma unroll
            for (int m = 0; m < 4; ++m)
                atomicAdd(&num[((size_t)(n * TT + rt * 16 + g * 4 + m)) * 64 + hs * 16 + c],
                          numacc[a][hs][m]);
    }
}

// ---------- z = num / den ------------------------------------------------------
__global__ void zdiv_kernel(const float* __restrict__ num, const float* __restrict__ den,
                            float* __restrict__ z) {
    int idx = blockIdx.x * 256 + threadIdx.x;
    float d = den[idx >> 6];
    z[idx] = (d > 0.f) ? num[idx] / d : 0.f;
}

// ---------- out[t][d] = b_O[d] + sum_{n,h} z[n][t][h]*W_O[n][h][d] -------------
__global__ void out_kernel(const float* __restrict__ z, const float* __restrict__ W_O,
                           const float* __restrict__ b_O, float* __restrict__ out) {
    int t = blockIdx.x;
    int tid = threadIdx.x;
    __shared__ float sz[NN * HH];
    for (int m = 0; m < 2; ++m) {
        int idx = m * 256 + tid;
        int n = idx >> 6, h = idx & 63;
        sz[idx] = z[((size_t)n * TT + t) * HH + h];
    }
    __syncthreads();
    for (int m = 0; m < 2; ++m) {
        int d = m * 256 + tid;
        float acc = b_O[d];
        for (int qq = 0; qq < NN * HH; ++qq) acc += sz[qq] * W_O[(size_t)qq * DD + d];
        out[(size_t)t * DD + d] = acc;
    }
}

extern "C" void kernel_launch(void* const* d_in, const int* in_sizes, int n_in,
                              void* d_out, int out_size, void* d_ws, size_t ws_size,
                              hipStream_t stream) {
    const float* x    = (const float*)d_in[0];
    const float* W_K1 = (const float*)d_in[1];
    const float* W_K2 = (const float*)d_in[2];
    const float* W_Q  = (const float*)d_in[3];
    const float* W_V1 = (const float*)d_in[4];
    const float* W_V2 = (const float*)d_in[5];
    const float* W_Kq = (const float*)d_in[6];
    const float* W_Vq = (const float*)d_in[7];
    const float* W_O  = (const float*)d_in[8];
    const float* b_K1 = (const float*)d_in[9];
    const float* b_K2 = (const float*)d_in[10];
    const float* b_Q  = (const float*)d_in[11];
    const float* b_V1 = (const float*)d_in[12];
    const float* b_V2 = (const float*)d_in[13];
    const float* b_O  = (const float*)d_in[14];
    float* ws = (float*)d_ws;
    short* sb = (short*)(ws + F_TOTAL);
    float* out = (float*)d_out;

    dim3 pg(NN, TT / 4);
    proj_kernel<<<pg, 256, 0, stream>>>(x, W_K1, b_K1, ws + F_K1, sb + S_K1B);
    proj_kernel<<<pg, 256, 0, stream>>>(x, W_K2, b_K2, ws + F_K2, sb + S_K2B);
    proj_kernel<<<pg, 256, 0, stream>>>(x, W_Q,  b_Q,  ws + F_Q,  (short*)nullptr);
    proj_kernel<<<pg, 256, 0, stream>>>(x, W_V1, b_V1, ws + F_V1, sb + S_V1B);
    proj_kernel<<<pg, 256, 0, stream>>>(x, W_V2, b_V2, ws + F_V2, (short*)nullptr);

    step1_kernel<<<dim3(NN, HH), 256, 0, stream>>>(ws + F_Q, W_Kq, sb + S_S1B);
    amat_kernel <<<dim3(NN, HH), 256, 0, stream>>>(ws + F_V2, W_Vq, ws + F_A);
    trA_kernel  <<<NN * TT, 256, 0, stream>>>(ws + F_A, sb + S_AB);

    gmat_kernel<<<dim3(256, NN), 256, 0, stream>>>(sb + S_S1B, sb + S_K2B, sb + S_GB);
    umat_kernel<<<dim3(TT, NN), 256, 0, stream>>>(sb + S_V1B, sb + S_AB, sb + S_UB);

    hipMemsetAsync(ws + F_NUM, 0, (size_t)(131072 + 2048) * sizeof(float), stream);

    attn_kernel<<<dim3(64, NN), 512, 0, stream>>>(sb + S_K1B, sb + S_GB, sb + S_UB,
                                                  ws + F_NUM, ws + F_DEN);

    zdiv_kernel<<<512, 256, 0, stream>>>(ws + F_NUM, ws + F_DEN, ws + F_Z);
    out_kernel<<<TT, 256, 0, stream>>>(ws + F_Z, W_O, b_O, out);
}

// Round 3
// 212.404 us; speedup vs baseline: 4.5764x; 1.5486x over previous
//
#include <hip/hip_runtime.h>
#include <hip/hip_bf16.h>
#include <math.h>

#define TT 256   // seq len
#define DD 512   // d_model
#define NN 8     // heads
#define HH 64    // head dim
#define PROJ 131072

typedef __attribute__((ext_vector_type(8))) short short8v;   // 8 bf16
typedef __attribute__((ext_vector_type(4))) short short4v;   // 4 bf16
typedef __attribute__((ext_vector_type(4))) float f32x4;

__device__ __forceinline__ short f2bf(float x) {
    union { float f; unsigned u; } v; v.f = x;
    unsigned r = (v.u + 0x7FFFu + ((v.u >> 16) & 1u)) >> 16;   // RNE
    return (short)r;
}

#define LGKM0 asm volatile("s_waitcnt lgkmcnt(0)" ::: "memory")

// ---------------- workspace layout ----------------
// float region (floats)
#define F_NUM  0            // 131072
#define F_DEN  131072       // 2048
#define F_END  133120
// short region, base = (short*)(ws + F_END), offsets in shorts
#define S_PB   0            // 5*131072  (K1,K2,Q,V1,V2 bf16 [p][n][t][h])
#define S_XB   655360       // 131072    xb[t][d]
#define S_WB   786432       // 1310720   Wb[p][n][h][d]
#define S_KQB  2097152      // 2097152   Kqb[n][ij][k]  (natural layout)
#define S_VQB  4194304      // 2097152   Vqb[n][h][i][j] (transposed)
#define S_WOB  6291456      // 262144    WOb[d][nh]
#define S_S1B  6553600      // 8388608   S1b[n][r][ij]
#define S_AB   14942208     // 8388608   Ab[n][t][h*64+i]
#define S_GB   23330816     // 33554432  G[n][r][t][i]
#define S_ZB   56885248     // 131072    zb[t][n*64+h]

// ---------------- generic fp32 -> bf16 convert (8/thread) ---------------------
__global__ void cvt_kernel(const float* __restrict__ src, short* __restrict__ dst, int n8) {
    int i = blockIdx.x * 256 + threadIdx.x;
    if (i >= n8) return;
    const float4 f0 = *(const float4*)(src + (size_t)i * 8);
    const float4 f1 = *(const float4*)(src + (size_t)i * 8 + 4);
    short8v o;
    o[0] = f2bf(f0.x); o[1] = f2bf(f0.y); o[2] = f2bf(f0.z); o[3] = f2bf(f0.w);
    o[4] = f2bf(f1.x); o[5] = f2bf(f1.y); o[6] = f2bf(f1.z); o[7] = f2bf(f1.w);
    *(short8v*)(dst + (size_t)i * 8) = o;
}

// ---------------- Wb[p][n][h][d] <- W_p[n][d][h] (transpose-convert) ----------
__global__ void wconv_kernel(const float* __restrict__ W0, const float* __restrict__ W1,
                             const float* __restrict__ W2, const float* __restrict__ W3,
                             const float* __restrict__ W4, short* __restrict__ Wb) {
    int pn = blockIdx.x; int p = pn >> 3, n = pn & 7;
    const float* Wp = (p == 0) ? W0 : (p == 1) ? W1 : (p == 2) ? W2 : (p == 3) ? W3 : W4;
    const float* src = Wp + (size_t)n * DD * HH;     // [d][h]
    short* dst = Wb + (size_t)pn * HH * DD;          // [h][d]
    __shared__ float lds[64 * 65];
    for (int d0 = 0; d0 < DD; d0 += 64) {
        __syncthreads();
        for (int it = 0; it < 16; ++it) {
            int m = it * 256 + threadIdx.x;
            int dl = m >> 6, h = m & 63;
            lds[h * 65 + dl] = src[(size_t)(d0 + dl) * 64 + h];
        }
        __syncthreads();
        int h = threadIdx.x >> 2, seg = threadIdx.x & 3;
        short8v o0, o1;
        #pragma unroll
        for (int e = 0; e < 8; ++e) o0[e] = f2bf(lds[h * 65 + seg * 16 + e]);
        #pragma unroll
        for (int e = 0; e < 8; ++e) o1[e] = f2bf(lds[h * 65 + seg * 16 + 8 + e]);
        *(short8v*)(dst + (size_t)h * DD + d0 + seg * 16) = o0;
        *(short8v*)(dst + (size_t)h * DD + d0 + seg * 16 + 8) = o1;
    }
}

// ---------------- Vqb[n][h][i][j] <- W_Vq[n][i][j][h] -------------------------
__global__ void vqconv_kernel(const float* __restrict__ Vq, short* __restrict__ Vqb) {
    int b = blockIdx.x; int n = b >> 6, i = b & 63;
    const float* src = Vq + (size_t)(n * 64 + i) * 4096;   // [j][h]
    __shared__ float lds[64 * 65];
    for (int it = 0; it < 16; ++it) {
        int m = it * 256 + threadIdx.x;
        int j = m >> 6, h = m & 63;
        lds[h * 65 + j] = src[(size_t)j * 64 + h];
    }
    __syncthreads();
    int h = threadIdx.x >> 2, seg = threadIdx.x & 3;
    short8v o0, o1;
    #pragma unroll
    for (int e = 0; e < 8; ++e) o0[e] = f2bf(lds[h * 65 + seg * 16 + e]);
    #pragma unroll
    for (int e = 0; e < 8; ++e) o1[e] = f2bf(lds[h * 65 + seg * 16 + 8 + e]);
    short* dst = Vqb + (size_t)n * 262144 + (size_t)h * 4096 + i * 64 + seg * 16;
    *(short8v*)dst = o0;
    *(short8v*)(dst + 8) = o1;
}

// ---------------- WOb[d][nh] <- W_O[nh][d] -------------------------------------
__global__ void woconv_kernel(const float* __restrict__ WO, short* __restrict__ WOb) {
    int dc = blockIdx.x & 7, nhc = blockIdx.x >> 3;
    __shared__ float lds[64 * 129];   // [dl][nhl]
    for (int it = 0; it < 32; ++it) {
        int m = it * 256 + threadIdx.x;
        int nhl = m >> 6, dl = m & 63;
        lds[dl * 129 + nhl] = WO[(size_t)(nhc * 128 + nhl) * 512 + dc * 64 + dl];
    }
    __syncthreads();
    for (int it = 0; it < 4; ++it) {
        int m = it * 256 + threadIdx.x;
        int dl = m >> 4, seg = m & 15;
        short8v o;
        #pragma unroll
        for (int e = 0; e < 8; ++e) o[e] = f2bf(lds[dl * 129 + seg * 8 + e]);
        *(short8v*)(WOb + (size_t)(dc * 64 + dl) * 512 + nhc * 128 + seg * 8) = o;
    }
}

// ---------------- proj (MFMA): Pb[p][n][t][h] = xb[t][:] . Wb[p][n][h][:] + b --
__global__ __launch_bounds__(512) void proj_kernel(
    const short* __restrict__ xb, const short* __restrict__ Wb,
    const float* __restrict__ bK1, const float* __restrict__ bK2,
    const float* __restrict__ bQ,  const float* __restrict__ bV1,
    const float* __restrict__ bV2, short* __restrict__ Pb) {
    int p = blockIdx.x, n = blockIdx.y, mhalf = blockIdx.z;
    int wv = threadIdx.x >> 6, lane = threadIdx.x & 63, g = lane >> 4, c = lane & 15;
    __shared__ short wlds[64 * 520];
    __shared__ short sbuf[8][16 * 72];
    const short* wsrc = Wb + (size_t)(p * 8 + n) * HH * DD;
    for (int it = 0; it < 8; ++it) {
        int idx = it * 512 + threadIdx.x;
        int h = idx >> 6, seg = idx & 63;
        *(short8v*)(&wlds[h * 520 + seg * 8]) = *(const short8v*)(wsrc + (size_t)h * DD + seg * 8);
    }
    __syncthreads();
    int mt = mhalf * 8 + wv;
    f32x4 acc[4];
    #pragma unroll
    for (int ct = 0; ct < 4; ++ct) acc[ct] = (f32x4){0.f, 0.f, 0.f, 0.f};
    for (int ks = 0; ks < 16; ++ks) {
        short8v a = *(const short8v*)(xb + (size_t)(mt * 16 + c) * DD + ks * 32 + g * 8);
        #pragma unroll
        for (int ct = 0; ct < 4; ++ct) {
            short8v b = *(const short8v*)(&wlds[(ct * 16 + c) * 520 + ks * 32 + g * 8]);
            acc[ct] = __builtin_amdgcn_mfma_f32_16x16x32_bf16(a, b, acc[ct], 0, 0, 0);
        }
    }
    const float* bp = (p == 0) ? bK1 : (p == 1) ? bK2 : (p == 2) ? bQ : (p == 3) ? bV1 : bV2;
    short* sb = &sbuf[wv][0];
    #pragma unroll
    for (int ct = 0; ct < 4; ++ct) {
        float bias = bp[n * 64 + ct * 16 + c];
        #pragma unroll
        for (int m = 0; m < 4; ++m)
            sb[(g * 4 + m) * 72 + ct * 16 + c] = f2bf(acc[ct][m] + bias);
    }
    LGKM0;
    int rl = lane & 15, sg = lane >> 4;
    short8v o0 = *(const short8v*)(&sb[rl * 72 + sg * 16]);
    short8v o1 = *(const short8v*)(&sb[rl * 72 + sg * 16 + 8]);
    short* dst = Pb + (size_t)p * PROJ + (size_t)(n * 256 + mt * 16 + rl) * 64 + sg * 16;
    *(short8v*)dst = o0;
    *(short8v*)(dst + 8) = o1;
}

// ------ generic: out[n][m(256)][cflat(4096)] = A[n][m][k64] . B[n][cflat][k64]^T
__global__ __launch_bounds__(256) void bgemm_kernel(const short* __restrict__ A,
                                                    const short* __restrict__ B,
                                                    short* __restrict__ out) {
    int mt = blockIdx.x, n = blockIdx.y;
    int wv = threadIdx.x >> 6, lane = threadIdx.x & 63, g = lane >> 4, c = lane & 15;
    __shared__ short sbuf[4][16 * 72];
    short* sb = &sbuf[wv][0];
    const short* abase = A + ((size_t)n * 256 + mt * 16 + c) * 64 + g * 8;
    short8v a0 = *(const short8v*)abase;
    short8v a1 = *(const short8v*)(abase + 32);
    for (int cg = wv; cg < 64; cg += 4) {
        f32x4 acc[4];
        #pragma unroll
        for (int jt = 0; jt < 4; ++jt) acc[jt] = (f32x4){0.f, 0.f, 0.f, 0.f};
        const short* bb = B + ((size_t)n * 4096 + cg * 64) * 64;
        #pragma unroll
        for (int jt = 0; jt < 4; ++jt) {
            short8v b0 = *(const short8v*)(bb + (size_t)(jt * 16 + c) * 64 + g * 8);
            short8v b1 = *(const short8v*)(bb + (size_t)(jt * 16 + c) * 64 + g * 8 + 32);
            acc[jt] = __builtin_amdgcn_mfma_f32_16x16x32_bf16(a0, b0, acc[jt], 0, 0, 0);
            acc[jt] = __builtin_amdgcn_mfma_f32_16x16x32_bf16(a1, b1, acc[jt], 0, 0, 0);
        }
        LGKM0;   // prior iteration's sbuf reads complete
        #pragma unroll
        for (int jt = 0; jt < 4; ++jt)
            #pragma unroll
            for (int m = 0; m < 4; ++m)
                sb[(g * 4 + m) * 72 + jt * 16 + c] = f2bf(acc[jt][m]);
        LGKM0;
        int rl = lane & 15, sg = lane >> 4;
        short8v o0 = *(const short8v*)(&sb[rl * 72 + sg * 16]);
        short8v o1 = *(const short8v*)(&sb[rl * 72 + sg * 16 + 8]);
        short* dst = out + ((size_t)n * 256 + mt * 16 + rl) * 4096 + cg * 64 + sg * 16;
        *(short8v*)dst = o0;
        *(short8v*)(dst + 8) = o1;
    }
}

// ---------- G[n][r][t][i] = sum_j S1[n][r][i][j]*k2[n][t][j]  (MFMA) ----------
__global__ __launch_bounds__(256) void gmat_kernel(const short* __restrict__ S1b,
                                                   const short* __restrict__ K2b,
                                                   short* __restrict__ G) {
    int n = blockIdx.y;
    int wave = threadIdx.x >> 6, lane = threadIdx.x & 63;
    int g = lane >> 4, c = lane & 15;
    int mt = blockIdx.x * 4 + wave;          // m-tile 0..1023
    int r = mt >> 2, i0 = (mt & 3) * 16;
    __shared__ short tl[4][16 * 17];
    short* my = tl[wave];
    const short* abase = S1b + ((size_t)n * 16384 + mt * 16 + c) * 64 + g * 8;
    short8v a0 = *(const short8v*)abase;
    short8v a1 = *(const short8v*)(abase + 32);
    for (int tt = 0; tt < 16; ++tt) {
        const short* bbase = K2b + ((size_t)n * TT + tt * 16 + c) * 64 + g * 8;
        short8v b0 = *(const short8v*)bbase;
        short8v b1 = *(const short8v*)(bbase + 32);
        f32x4 acc = {0.f, 0.f, 0.f, 0.f};
        acc = __builtin_amdgcn_mfma_f32_16x16x32_bf16(a0, b0, acc, 0, 0, 0);
        acc = __builtin_amdgcn_mfma_f32_16x16x32_bf16(a1, b1, acc, 0, 0, 0);
        LGKM0;
        #pragma unroll
        for (int m = 0; m < 4; ++m) my[c * 17 + g * 4 + m] = f2bf(acc[m]);
        LGKM0;
        int trow = lane >> 2, qq = (lane & 3) * 4;
        short4v ov;
        #pragma unroll
        for (int e = 0; e < 4; ++e) ov[e] = my[trow * 17 + qq + e];
        *(short4v*)(&G[(((size_t)(n * TT + r) * TT) + tt * 16 + trow) * 64 + i0 + qq]) = ov;
    }
}

// ---------- fused cubic attention (U computed in-register) --------------------
__global__ __launch_bounds__(512) void attn_kernel(
    const short* __restrict__ K1b, const short* __restrict__ V1b,
    const short* __restrict__ Gm, const short* __restrict__ Ab,
    float* __restrict__ num, float* __restrict__ den)
{
    int n = blockIdx.y;
    int ttile = blockIdx.x >> 1;
    int sig = blockIdx.x & 1;
    int t0 = ttile * 8;
    int tid = threadIdx.x;
    int wv = tid >> 6, lane = tid & 63, g = lane >> 4, c = lane & 15;

    __shared__ short k1lds[128 * 72];
    __shared__ short v1lds[128 * 72];
    __shared__ short ablds[64 * 72];

    int stmaxK = (t0 + 6) >> 4;
    int cntK = (stmaxK >= sig) ? ((stmaxK - sig) >> 1) + 1 : 0;
    for (int idx = tid; idx < cntK * 128; idx += 512) {
        int row = idx >> 3, seg = idx & 7;
        int s = (sig + ((row >> 4) << 1)) * 16 + (row & 15);
        *(short8v*)(&k1lds[row * 72 + seg * 8]) =
            *(const short8v*)(K1b + ((size_t)n * TT + s) * 64 + seg * 8);
        *(short8v*)(&v1lds[row * 72 + seg * 8]) =
            *(const short8v*)(V1b + ((size_t)n * TT + s) * 64 + seg * 8);
    }
    __syncthreads();

    f32x4 numacc[2][4];
    #pragma unroll
    for (int a = 0; a < 2; ++a)
        #pragma unroll
        for (int b = 0; b < 4; ++b) numacc[a][b] = (f32x4){0.f, 0.f, 0.f, 0.f};
    float denacc[2] = {0.f, 0.f};
    int rts0 = wv, rts1 = wv + 8;

    for (int th = 0; th < 8; ++th) {
        int t = t0 + th;
        if (t < 1 || t > 254) continue;
        int rt_start = (t + 1) >> 4;
        int stmaxU = (t - 1) >> 4;
        int cntU = (stmaxU >= sig) ? ((stmaxU - sig) >> 1) + 1 : 0;
        if (cntU == 0) continue;

        __syncthreads();   // protect ablds from previous t's reads
        {
            int row = tid >> 3, seg = tid & 7;
            *(short8v*)(&ablds[row * 72 + seg * 8]) =
                *(const short8v*)(Ab + ((size_t)(n * TT + t)) * 4096 + row * 64 + seg * 8);
        }
        __syncthreads();

        short8v gf0[2], gf1[2];
        bool v0 = (rts0 >= rt_start), v1 = (rts1 >= rt_start);
        if (v0) {
            const short* gb = Gm + (((size_t)(n * TT + rts0 * 16 + c) * TT) + t) * 64 + g * 8;
            gf0[0] = *(const short8v*)gb; gf0[1] = *(const short8v*)(gb + 32);
        }
        if (v1) {
            const short* gb = Gm + (((size_t)(n * TT + rts1 * 16 + c) * TT) + t) * 64 + g * 8;
            gf1[0] = *(const short8v*)gb; gf1[1] = *(const short8v*)(gb + 32);
        }

        for (int loc = 0; loc < cntU; ++loc) {
            int s_base = (sig + loc * 2) * 16;
            const short* kr = &k1lds[(loc * 16 + c) * 72 + g * 8];
            short8v af0 = *(const short8v*)kr;
            short8v af1 = *(const short8v*)(kr + 32);
            const short* vr = &v1lds[(loc * 16 + c) * 72 + g * 8];
            short8v vf0 = *(const short8v*)vr;
            short8v vf1 = *(const short8v*)(vr + 32);

            // U fragments: ucc(s,h) = sum_i v1[s,i] * A[t,i,h]; C-frag == PV B-frag
            short4v ub[4];
            #pragma unroll
            for (int hs = 0; hs < 4; ++hs) {
                short8v ab0 = *(const short8v*)(&ablds[(hs * 16 + c) * 72 + g * 8]);
                short8v ab1 = *(const short8v*)(&ablds[(hs * 16 + c) * 72 + g * 8 + 32]);
                f32x4 ucc = {0.f, 0.f, 0.f, 0.f};
                ucc = __builtin_amdgcn_mfma_f32_16x16x32_bf16(vf0, ab0, ucc, 0, 0, 0);
                ucc = __builtin_amdgcn_mfma_f32_16x16x32_bf16(vf1, ab1, ucc, 0, 0, 0);
                #pragma unroll
                for (int m = 0; m < 4; ++m) ub[hs][m] = f2bf(ucc[m]);
            }

            #pragma unroll
            for (int a = 0; a < 2; ++a) {
                bool va = a ? v1 : v0;
                if (!va) continue;
                int rt = a ? rts1 : rts0;
                f32x4 lg = {0.f, 0.f, 0.f, 0.f};
                lg = __builtin_amdgcn_mfma_f32_16x16x32_bf16(af0, a ? gf1[0] : gf0[0], lg, 0, 0, 0);
                lg = __builtin_amdgcn_mfma_f32_16x16x32_bf16(af1, a ? gf1[1] : gf0[1], lg, 0, 0, 0);
                int r = rt * 16 + c;
                short4v eb;
                float dsum = 0.f;
                #pragma unroll
                for (int m = 0; m < 4; ++m) {
                    int s = s_base + g * 4 + m;
                    float e = (s < t && r > t) ? __expf(lg[m] * 0.015625f) : 0.f;
                    dsum += e;
                    eb[m] = f2bf(e);
                }
                denacc[a] += dsum;
                #pragma unroll
                for (int hs = 0; hs < 4; ++hs)
                    numacc[a][hs] = __builtin_amdgcn_mfma_f32_16x16x16bf16_1k(eb, ub[hs], numacc[a][hs], 0, 0, 0);
            }
        }
    }

    // epilogue: atomics
    #pragma unroll
    for (int a = 0; a < 2; ++a) {
        int rt = a ? rts1 : rts0;
        if (rt * 16 + 15 <= t0) continue;
        float v = denacc[a];
        v += __shfl_xor(v, 16);
        v += __shfl_xor(v, 32);
        if (lane < 16) atomicAdd(&den[n * TT + rt * 16 + lane], v);
        #pragma unroll
        for (int hs = 0; hs < 4; ++hs)
            #pragma unroll
            for (int m = 0; m < 4; ++m)
                atomicAdd(&num[((size_t)(n * TT + rt * 16 + g * 4 + m)) * 64 + hs * 16 + c],
                          numacc[a][hs][m]);
    }
}

// ---------- zb[t][n*64+h] = bf16(num/den) --------------------------------------
__global__ void zdiv_kernel(const float* __restrict__ num, const float* __restrict__ den,
                            short* __restrict__ zb) {
    int idx = blockIdx.x * 256 + threadIdx.x;   // over 131072 = [n][t][h]
    int n = idx >> 14, t = (idx >> 6) & 255, h = idx & 63;
    float d = den[idx >> 6];
    float z = (d > 0.f) ? num[idx] / d : 0.f;
    zb[(size_t)t * 512 + n * 64 + h] = f2bf(z);
}

// ---------- out[t][d] = b_O[d] + zb[t][:] . WOb[d][:]  (MFMA) ------------------
__global__ __launch_bounds__(512) void out_kernel(const short* __restrict__ zb,
                                                  const short* __restrict__ WOb,
                                                  const float* __restrict__ bO,
                                                  float* __restrict__ out) {
    int mt = blockIdx.x & 15, dq = blockIdx.x >> 4;
    int wv = threadIdx.x >> 6, lane = threadIdx.x & 63, g = lane >> 4, c = lane & 15;
    int dt0 = dq * 16 + wv * 2;
    f32x4 acc[2];
    acc[0] = (f32x4){0.f, 0.f, 0.f, 0.f};
    acc[1] = (f32x4){0.f, 0.f, 0.f, 0.f};
    for (int ks = 0; ks < 16; ++ks) {
        short8v a = *(const short8v*)(zb + (size_t)(mt * 16 + c) * 512 + ks * 32 + g * 8);
        #pragma unroll
        for (int u = 0; u < 2; ++u) {
            short8v b = *(const short8v*)(WOb + (size_t)((dt0 + u) * 16 + c) * 512 + ks * 32 + g * 8);
            acc[u] = __builtin_amdgcn_mfma_f32_16x16x32_bf16(a, b, acc[u], 0, 0, 0);
        }
    }
    #pragma unroll
    for (int u = 0; u < 2; ++u) {
        int d = (dt0 + u) * 16 + c;
        float bias = bO[d];
        #pragma unroll
        for (int m = 0; m < 4; ++m)
            out[(size_t)(mt * 16 + g * 4 + m) * 512 + d] = acc[u][m] + bias;
    }
}

extern "C" void kernel_launch(void* const* d_in, const int* in_sizes, int n_in,
                              void* d_out, int out_size, void* d_ws, size_t ws_size,
                              hipStream_t stream) {
    const float* x    = (const float*)d_in[0];
    const float* W_K1 = (const float*)d_in[1];
    const float* W_K2 = (const float*)d_in[2];
    const float* W_Q  = (const float*)d_in[3];
    const float* W_V1 = (const float*)d_in[4];
    const float* W_V2 = (const float*)d_in[5];
    const float* W_Kq = (const float*)d_in[6];
    const float* W_Vq = (const float*)d_in[7];
    const float* W_O  = (const float*)d_in[8];
    const float* b_K1 = (const float*)d_in[9];
    const float* b_K2 = (const float*)d_in[10];
    const float* b_Q  = (const float*)d_in[11];
    const float* b_V1 = (const float*)d_in[12];
    const float* b_V2 = (const float*)d_in[13];
    const float* b_O  = (const float*)d_in[14];
    float* ws = (float*)d_ws;
    short* sb = (short*)(ws + F_END);
    float* out = (float*)d_out;

    // converts
    cvt_kernel<<<64, 256, 0, stream>>>(x, sb + S_XB, 16384);
    cvt_kernel<<<1024, 256, 0, stream>>>(W_Kq, sb + S_KQB, 262144);
    wconv_kernel<<<40, 256, 0, stream>>>(W_K1, W_K2, W_Q, W_V1, W_V2, sb + S_WB);
    vqconv_kernel<<<512, 256, 0, stream>>>(W_Vq, sb + S_VQB);
    woconv_kernel<<<32, 256, 0, stream>>>(W_O, sb + S_WOB);

    // projections (bf16)
    proj_kernel<<<dim3(5, 8, 2), 512, 0, stream>>>(sb + S_XB, sb + S_WB,
                                                   b_K1, b_K2, b_Q, b_V1, b_V2, sb + S_PB);

    // step1[n][r][ij] and Ab[n][t][hi]
    bgemm_kernel<<<dim3(16, 8), 256, 0, stream>>>(sb + S_PB + 2 * PROJ, sb + S_KQB, sb + S_S1B);
    bgemm_kernel<<<dim3(16, 8), 256, 0, stream>>>(sb + S_PB + 4 * PROJ, sb + S_VQB, sb + S_AB);

    // G
    gmat_kernel<<<dim3(256, 8), 256, 0, stream>>>(sb + S_S1B, sb + S_PB + 1 * PROJ, sb + S_GB);

    hipMemsetAsync(ws + F_NUM, 0, (size_t)F_END * sizeof(float), stream);

    attn_kernel<<<dim3(64, 8), 512, 0, stream>>>(sb + S_PB, sb + S_PB + 3 * PROJ,
                                                 sb + S_GB, sb + S_AB,
                                                 ws + F_NUM, ws + F_DEN);

    zdiv_kernel<<<512, 256, 0, stream>>>(ws + F_NUM, ws + F_DEN, sb + S_ZB);
    out_kernel<<<32, 512, 0, stream>>>(sb + S_ZB, sb + S_WOB, b_O, out);
}

// Round 4
// 170.207 us; speedup vs baseline: 5.7110x; 1.2479x over previous
//
#include <hip/hip_runtime.h>
#include <hip/hip_bf16.h>
#include <math.h>

#define TT 256   // seq len
#define DD 512   // d_model
#define NN 8     // heads
#define HH 64    // head dim
#define PROJ 131072

typedef __attribute__((ext_vector_type(8))) short short8v;   // 8 bf16
typedef __attribute__((ext_vector_type(4))) short short4v;   // 4 bf16
typedef __attribute__((ext_vector_type(4))) float f32x4;

__device__ __forceinline__ short f2bf(float x) {
    union { float f; unsigned u; } v; v.f = x;
    unsigned r = (v.u + 0x7FFFu + ((v.u >> 16) & 1u)) >> 16;   // RNE
    return (short)r;
}

#define LGKM0 asm volatile("s_waitcnt lgkmcnt(0)" ::: "memory")

// ---------------- workspace layout ----------------
// float region (floats)
#define F_NUM  0            // 131072
#define F_DEN  131072       // 2048
#define F_END  133120
// short region, base = (short*)(ws + F_END), offsets in shorts
#define S_PB   0            // 5*131072  (K1,K2,Q,V1,V2 bf16 [p][n][t][h])
#define S_XB   655360       // 131072    xb[t][d]
#define S_WB   786432       // 1310720   Wb[p][n][h][d]
#define S_KQB  2097152      // 2097152   Kqb[n][ij][k]
#define S_VQB  4194304      // 2097152   Vqb[n][h][i][j]
#define S_WOB  6291456      // 262144    WOb[d][nh]
#define S_S1B  6553600      // 8388608   S1b[n][r][ij]
#define S_AB   14942208     // 8388608   Ab[n][t][h*64+i]
#define S_GB   23330816     // 33554432  G[n][t][r][i]   (t-major!)
#define S_ZB   56885248     // 131072    zb[t][n*64+h]

// ---------------- generic fp32 -> bf16 convert (8/thread) ---------------------
__global__ void cvt_kernel(const float* __restrict__ src, short* __restrict__ dst, int n8) {
    int i = blockIdx.x * 256 + threadIdx.x;
    if (i >= n8) return;
    const float4 f0 = *(const float4*)(src + (size_t)i * 8);
    const float4 f1 = *(const float4*)(src + (size_t)i * 8 + 4);
    short8v o;
    o[0] = f2bf(f0.x); o[1] = f2bf(f0.y); o[2] = f2bf(f0.z); o[3] = f2bf(f0.w);
    o[4] = f2bf(f1.x); o[5] = f2bf(f1.y); o[6] = f2bf(f1.z); o[7] = f2bf(f1.w);
    *(short8v*)(dst + (size_t)i * 8) = o;
}

// ---------------- Wb[p][n][h][d] <- W_p[n][d][h] (transpose-convert) ----------
__global__ void wconv_kernel(const float* __restrict__ W0, const float* __restrict__ W1,
                             const float* __restrict__ W2, const float* __restrict__ W3,
                             const float* __restrict__ W4, short* __restrict__ Wb) {
    int pn = blockIdx.x; int p = pn >> 3, n = pn & 7;
    const float* Wp = (p == 0) ? W0 : (p == 1) ? W1 : (p == 2) ? W2 : (p == 3) ? W3 : W4;
    const float* src = Wp + (size_t)n * DD * HH;     // [d][h]
    short* dst = Wb + (size_t)pn * HH * DD;          // [h][d]
    __shared__ float lds[64 * 65];
    for (int d0 = 0; d0 < DD; d0 += 64) {
        __syncthreads();
        for (int it = 0; it < 16; ++it) {
            int m = it * 256 + threadIdx.x;
            int dl = m >> 6, h = m & 63;
            lds[h * 65 + dl] = src[(size_t)(d0 + dl) * 64 + h];
        }
        __syncthreads();
        int h = threadIdx.x >> 2, seg = threadIdx.x & 3;
        short8v o0, o1;
        #pragma unroll
        for (int e = 0; e < 8; ++e) o0[e] = f2bf(lds[h * 65 + seg * 16 + e]);
        #pragma unroll
        for (int e = 0; e < 8; ++e) o1[e] = f2bf(lds[h * 65 + seg * 16 + 8 + e]);
        *(short8v*)(dst + (size_t)h * DD + d0 + seg * 16) = o0;
        *(short8v*)(dst + (size_t)h * DD + d0 + seg * 16 + 8) = o1;
    }
}

// ---------------- Vqb[n][h][i][j] <- W_Vq[n][i][j][h] -------------------------
__global__ void vqconv_kernel(const float* __restrict__ Vq, short* __restrict__ Vqb) {
    int b = blockIdx.x; int n = b >> 6, i = b & 63;
    const float* src = Vq + (size_t)(n * 64 + i) * 4096;   // [j][h]
    __shared__ float lds[64 * 65];
    for (int it = 0; it < 16; ++it) {
        int m = it * 256 + threadIdx.x;
        int j = m >> 6, h = m & 63;
        lds[h * 65 + j] = src[(size_t)j * 64 + h];
    }
    __syncthreads();
    int h = threadIdx.x >> 2, seg = threadIdx.x & 3;
    short8v o0, o1;
    #pragma unroll
    for (int e = 0; e < 8; ++e) o0[e] = f2bf(lds[h * 65 + seg * 16 + e]);
    #pragma unroll
    for (int e = 0; e < 8; ++e) o1[e] = f2bf(lds[h * 65 + seg * 16 + 8 + e]);
    short* dst = Vqb + (size_t)n * 262144 + (size_t)h * 4096 + i * 64 + seg * 16;
    *(short8v*)dst = o0;
    *(short8v*)(dst + 8) = o1;
}

// ---------------- WOb[d][nh] <- W_O[nh][d] -------------------------------------
__global__ void woconv_kernel(const float* __restrict__ WO, short* __restrict__ WOb) {
    int dc = blockIdx.x & 7, nhc = blockIdx.x >> 3;
    __shared__ float lds[64 * 129];   // [dl][nhl]
    for (int it = 0; it < 32; ++it) {
        int m = it * 256 + threadIdx.x;
        int nhl = m >> 6, dl = m & 63;
        lds[dl * 129 + nhl] = WO[(size_t)(nhc * 128 + nhl) * 512 + dc * 64 + dl];
    }
    __syncthreads();
    for (int it = 0; it < 4; ++it) {
        int m = it * 256 + threadIdx.x;
        int dl = m >> 4, seg = m & 15;
        short8v o;
        #pragma unroll
        for (int e = 0; e < 8; ++e) o[e] = f2bf(lds[dl * 129 + seg * 8 + e]);
        *(short8v*)(WOb + (size_t)(dc * 64 + dl) * 512 + nhc * 128 + seg * 8) = o;
    }
}

// ---------------- proj (MFMA): Pb[p][n][t][h] = xb[t][:] . Wb[p][n][h][:] + b --
__global__ __launch_bounds__(512) void proj_kernel(
    const short* __restrict__ xb, const short* __restrict__ Wb,
    const float* __restrict__ bK1, const float* __restrict__ bK2,
    const float* __restrict__ bQ,  const float* __restrict__ bV1,
    const float* __restrict__ bV2, short* __restrict__ Pb) {
    int p = blockIdx.x, n = blockIdx.y, mhalf = blockIdx.z;
    int wv = threadIdx.x >> 6, lane = threadIdx.x & 63, g = lane >> 4, c = lane & 15;
    __shared__ short wlds[64 * 520];
    __shared__ short sbuf[8][16 * 72];
    const short* wsrc = Wb + (size_t)(p * 8 + n) * HH * DD;
    for (int it = 0; it < 8; ++it) {
        int idx = it * 512 + threadIdx.x;
        int h = idx >> 6, seg = idx & 63;
        *(short8v*)(&wlds[h * 520 + seg * 8]) = *(const short8v*)(wsrc + (size_t)h * DD + seg * 8);
    }
    __syncthreads();
    int mt = mhalf * 8 + wv;
    f32x4 acc[4];
    #pragma unroll
    for (int ct = 0; ct < 4; ++ct) acc[ct] = (f32x4){0.f, 0.f, 0.f, 0.f};
    for (int ks = 0; ks < 16; ++ks) {
        short8v a = *(const short8v*)(xb + (size_t)(mt * 16 + c) * DD + ks * 32 + g * 8);
        #pragma unroll
        for (int ct = 0; ct < 4; ++ct) {
            short8v b = *(const short8v*)(&wlds[(ct * 16 + c) * 520 + ks * 32 + g * 8]);
            acc[ct] = __builtin_amdgcn_mfma_f32_16x16x32_bf16(a, b, acc[ct], 0, 0, 0);
        }
    }
    const float* bp = (p == 0) ? bK1 : (p == 1) ? bK2 : (p == 2) ? bQ : (p == 3) ? bV1 : bV2;
    short* sb = &sbuf[wv][0];
    #pragma unroll
    for (int ct = 0; ct < 4; ++ct) {
        float bias = bp[n * 64 + ct * 16 + c];
        #pragma unroll
        for (int m = 0; m < 4; ++m)
            sb[(g * 4 + m) * 72 + ct * 16 + c] = f2bf(acc[ct][m] + bias);
    }
    LGKM0;
    int rl = lane & 15, sg = lane >> 4;
    short8v o0 = *(const short8v*)(&sb[rl * 72 + sg * 16]);
    short8v o1 = *(const short8v*)(&sb[rl * 72 + sg * 16 + 8]);
    short* dst = Pb + (size_t)p * PROJ + (size_t)(n * 256 + mt * 16 + rl) * 64 + sg * 16;
    *(short8v*)dst = o0;
    *(short8v*)(dst + 8) = o1;
}

// ------ generic: out[n][m(256)][cflat(4096)] = A[n][m][k64] . B[n][cflat][k64]^T
__global__ __launch_bounds__(256) void bgemm_kernel(const short* __restrict__ A,
                                                    const short* __restrict__ B,
                                                    short* __restrict__ out) {
    int mt = blockIdx.x, n = blockIdx.y, cgq = blockIdx.z;
    int wv = threadIdx.x >> 6, lane = threadIdx.x & 63, g = lane >> 4, c = lane & 15;
    __shared__ short sbuf[4][16 * 72];
    short* sb = &sbuf[wv][0];
    const short* abase = A + ((size_t)n * 256 + mt * 16 + c) * 64 + g * 8;
    short8v a0 = *(const short8v*)abase;
    short8v a1 = *(const short8v*)(abase + 32);
    for (int cg = cgq * 16 + wv; cg < cgq * 16 + 16; cg += 4) {
        f32x4 acc[4];
        #pragma unroll
        for (int jt = 0; jt < 4; ++jt) acc[jt] = (f32x4){0.f, 0.f, 0.f, 0.f};
        const short* bb = B + ((size_t)n * 4096 + cg * 64) * 64;
        #pragma unroll
        for (int jt = 0; jt < 4; ++jt) {
            short8v b0 = *(const short8v*)(bb + (size_t)(jt * 16 + c) * 64 + g * 8);
            short8v b1 = *(const short8v*)(bb + (size_t)(jt * 16 + c) * 64 + g * 8 + 32);
            acc[jt] = __builtin_amdgcn_mfma_f32_16x16x32_bf16(a0, b0, acc[jt], 0, 0, 0);
            acc[jt] = __builtin_amdgcn_mfma_f32_16x16x32_bf16(a1, b1, acc[jt], 0, 0, 0);
        }
        LGKM0;
        #pragma unroll
        for (int jt = 0; jt < 4; ++jt)
            #pragma unroll
            for (int m = 0; m < 4; ++m)
                sb[(g * 4 + m) * 72 + jt * 16 + c] = f2bf(acc[jt][m]);
        LGKM0;
        int rl = lane & 15, sg = lane >> 4;
        short8v o0 = *(const short8v*)(&sb[rl * 72 + sg * 16]);
        short8v o1 = *(const short8v*)(&sb[rl * 72 + sg * 16 + 8]);
        short* dst = out + ((size_t)n * 256 + mt * 16 + rl) * 4096 + cg * 64 + sg * 16;
        *(short8v*)dst = o0;
        *(short8v*)(dst + 8) = o1;
    }
}

// ---------- G[n][t][r][i] = sum_j S1[n][r][i][j]*k2[n][t][j]  (MFMA, t<=r tiles)
// block = (r, n); wave wv owns i-tile wv; C(t-row, i-col) = K2(t,j) . S1^T(j,i)
__global__ __launch_bounds__(256) void gmat_kernel(const short* __restrict__ S1b,
                                                   const short* __restrict__ K2b,
                                                   short* __restrict__ G) {
    int r = blockIdx.x, n = blockIdx.y;
    if (r < 2) return;
    int wv = threadIdx.x >> 6, lane = threadIdx.x & 63, g = lane >> 4, c = lane & 15;
    // B-frag: B[j][i] = S1[r][i][j], i = wv*16 + c
    const short* bbase = S1b + (((size_t)n * 256 + r) * 64 + wv * 16 + c) * 64 + g * 8;
    short8v b0 = *(const short8v*)bbase;
    short8v b1 = *(const short8v*)(bbase + 32);
    int ttmax = r >> 4;
    for (int tt = 0; tt <= ttmax; ++tt) {
        const short* abase = K2b + ((size_t)n * 256 + tt * 16 + c) * 64 + g * 8;
        short8v a0 = *(const short8v*)abase;
        short8v a1 = *(const short8v*)(abase + 32);
        f32x4 acc = {0.f, 0.f, 0.f, 0.f};
        acc = __builtin_amdgcn_mfma_f32_16x16x32_bf16(a0, b0, acc, 0, 0, 0);
        acc = __builtin_amdgcn_mfma_f32_16x16x32_bf16(a1, b1, acc, 0, 0, 0);
        // lane (g,c) holds C(t = tt*16 + g*4 + m, i = wv*16 + c)
        #pragma unroll
        for (int m = 0; m < 4; ++m)
            G[(((size_t)n * 256 + tt * 16 + g * 4 + m) * 256 + r) * 64 + wv * 16 + c] = f2bf(acc[m]);
    }
}

// ---------- fused cubic attention: block = (pair of t-tiles, sig, n) -----------
__global__ __launch_bounds__(512) void attn_kernel(
    const short* __restrict__ K1b, const short* __restrict__ V1b,
    const short* __restrict__ Gm, const short* __restrict__ Ab,
    float* __restrict__ num, float* __restrict__ den)
{
    int n = blockIdx.y;
    int pair = blockIdx.x >> 1;
    int sig = blockIdx.x & 1;
    int tid = threadIdx.x;
    int wv = tid >> 6, lane = tid & 63, g = lane >> 4, c = lane & 15;

    __shared__ short k1lds[128 * 72];
    __shared__ short v1lds[128 * 72];
    __shared__ short ablds[64 * 72];
    __shared__ short u_lds[64 * 130];   // [h][s(+pad)]

    int t0H = (31 - pair) * 8;
    int stmaxK = (t0H + 6) >> 4;
    int cntK = (stmaxK >= sig) ? ((stmaxK - sig) >> 1) + 1 : 0;
    for (int idx = tid; idx < cntK * 128; idx += 512) {
        int row = idx >> 3, seg = idx & 7;
        int s = (sig + ((row >> 4) << 1)) * 16 + (row & 15);
        *(short8v*)(&k1lds[row * 72 + seg * 8]) =
            *(const short8v*)(K1b + ((size_t)n * TT + s) * 64 + seg * 8);
        *(short8v*)(&v1lds[row * 72 + seg * 8]) =
            *(const short8v*)(V1b + ((size_t)n * TT + s) * 64 + seg * 8);
    }
    __syncthreads();

    f32x4 numacc[2][4];
    #pragma unroll
    for (int a = 0; a < 2; ++a)
        #pragma unroll
        for (int b = 0; b < 4; ++b) numacc[a][b] = (f32x4){0.f, 0.f, 0.f, 0.f};
    float denacc[2] = {0.f, 0.f};
    int rts0 = wv, rts1 = wv + 8;

    for (int part = 0; part < 2; ++part) {
        int t0 = part ? t0H : pair * 8;
        for (int th = 0; th < 8; ++th) {
            int t = t0 + th;
            if (t < 1 || t > 254) continue;
            int rt_start = (t + 1) >> 4;
            int stmaxU = (t - 1) >> 4;
            int cntU = (stmaxU >= sig) ? ((stmaxU - sig) >> 1) + 1 : 0;
            if (cntU == 0) continue;

            __syncthreads();   // protect ablds / u_lds from previous t's reads
            {
                int row = tid >> 3, seg = tid & 7;
                *(short8v*)(&ablds[row * 72 + seg * 8]) =
                    *(const short8v*)(Ab + ((size_t)(n * TT + t)) * 4096 + row * 64 + seg * 8);
            }
            __syncthreads();

            // cooperative U: tasks (loc, hs) striped over 8 waves
            for (int task = wv; task < cntU * 4; task += 8) {
                int loc = task >> 2, hs = task & 3;
                const short* vr = &v1lds[(loc * 16 + c) * 72 + g * 8];
                short8v vf0 = *(const short8v*)vr;
                short8v vf1 = *(const short8v*)(vr + 32);
                short8v ab0 = *(const short8v*)(&ablds[(hs * 16 + c) * 72 + g * 8]);
                short8v ab1 = *(const short8v*)(&ablds[(hs * 16 + c) * 72 + g * 8 + 32]);
                f32x4 ucc = {0.f, 0.f, 0.f, 0.f};
                ucc = __builtin_amdgcn_mfma_f32_16x16x32_bf16(vf0, ab0, ucc, 0, 0, 0);
                ucc = __builtin_amdgcn_mfma_f32_16x16x32_bf16(vf1, ab1, ucc, 0, 0, 0);
                short4v uo;
                #pragma unroll
                for (int m = 0; m < 4; ++m) uo[m] = f2bf(ucc[m]);
                *(short4v*)(&u_lds[(hs * 16 + c) * 130 + loc * 16 + g * 4]) = uo;
            }
            __syncthreads();

            bool v0 = (rts0 >= rt_start), v1 = (rts1 >= rt_start);
            if (!v0 && !v1) continue;   // no barriers below within this th

            short8v gf0[2], gf1[2];
            if (v0) {
                const short* gb = Gm + (((size_t)(n * TT + t) * TT) + rts0 * 16 + c) * 64 + g * 8;
                gf0[0] = *(const short8v*)gb; gf0[1] = *(const short8v*)(gb + 32);
            }
            if (v1) {
                const short* gb = Gm + (((size_t)(n * TT + t) * TT) + rts1 * 16 + c) * 64 + g * 8;
                gf1[0] = *(const short8v*)gb; gf1[1] = *(const short8v*)(gb + 32);
            }

            for (int loc = 0; loc < cntU; ++loc) {
                int s_base = (sig + loc * 2) * 16;
                const short* kr = &k1lds[(loc * 16 + c) * 72 + g * 8];
                short8v af0 = *(const short8v*)kr;
                short8v af1 = *(const short8v*)(kr + 32);
                short4v ub[4];
                #pragma unroll
                for (int hs = 0; hs < 4; ++hs)
                    ub[hs] = *(const short4v*)(&u_lds[(hs * 16 + c) * 130 + loc * 16 + g * 4]);

                #pragma unroll
                for (int a = 0; a < 2; ++a) {
                    bool va = a ? v1 : v0;
                    if (!va) continue;
                    int rt = a ? rts1 : rts0;
                    f32x4 lg = {0.f, 0.f, 0.f, 0.f};
                    lg = __builtin_amdgcn_mfma_f32_16x16x32_bf16(af0, a ? gf1[0] : gf0[0], lg, 0, 0, 0);
                    lg = __builtin_amdgcn_mfma_f32_16x16x32_bf16(af1, a ? gf1[1] : gf0[1], lg, 0, 0, 0);
                    int r = rt * 16 + c;
                    short4v eb;
                    float dsum = 0.f;
                    #pragma unroll
                    for (int m = 0; m < 4; ++m) {
                        int s = s_base + g * 4 + m;
                        float e = (s < t && r > t) ? __expf(lg[m] * 0.015625f) : 0.f;
                        dsum += e;
                        eb[m] = f2bf(e);
                    }
                    denacc[a] += dsum;
                    #pragma unroll
                    for (int hs = 0; hs < 4; ++hs)
                        numacc[a][hs] = __builtin_amdgcn_mfma_f32_16x16x16bf16_1k(eb, ub[hs], numacc[a][hs], 0, 0, 0);
                }
            }
        }
    }

    // epilogue: atomics (zero contributions add 0 harmlessly)
    #pragma unroll
    for (int a = 0; a < 2; ++a) {
        int rt = a ? rts1 : rts0;
        float v = denacc[a];
        v += __shfl_xor(v, 16);
        v += __shfl_xor(v, 32);
        if (lane < 16) atomicAdd(&den[n * TT + rt * 16 + lane], v);
        #pragma unroll
        for (int hs = 0; hs < 4; ++hs)
            #pragma unroll
            for (int m = 0; m < 4; ++m)
                atomicAdd(&num[((size_t)(n * TT + rt * 16 + g * 4 + m)) * 64 + hs * 16 + c],
                          numacc[a][hs][m]);
    }
}

// ---------- zb[t][n*64+h] = bf16(num/den) --------------------------------------
__global__ void zdiv_kernel(const float* __restrict__ num, const float* __restrict__ den,
                            short* __restrict__ zb) {
    int idx = blockIdx.x * 256 + threadIdx.x;   // over 131072 = [n][t][h]
    int n = idx >> 14, t = (idx >> 6) & 255, h = idx & 63;
    float d = den[idx >> 6];
    float z = (d > 0.f) ? num[idx] / d : 0.f;
    zb[(size_t)t * 512 + n * 64 + h] = f2bf(z);
}

// ---------- out[t][d] = b_O[d] + zb[t][:] . WOb[d][:]  (MFMA) ------------------
__global__ __launch_bounds__(512) void out_kernel(const short* __restrict__ zb,
                                                  const short* __restrict__ WOb,
                                                  const float* __restrict__ bO,
                                                  float* __restrict__ out) {
    int mt = blockIdx.x & 15, dq = blockIdx.x >> 4;
    int wv = threadIdx.x >> 6, lane = threadIdx.x & 63, g = lane >> 4, c = lane & 15;
    int dt0 = dq * 16 + wv * 2;
    f32x4 acc[2];
    acc[0] = (f32x4){0.f, 0.f, 0.f, 0.f};
    acc[1] = (f32x4){0.f, 0.f, 0.f, 0.f};
    for (int ks = 0; ks < 16; ++ks) {
        short8v a = *(const short8v*)(zb + (size_t)(mt * 16 + c) * 512 + ks * 32 + g * 8);
        #pragma unroll
        for (int u = 0; u < 2; ++u) {
            short8v b = *(const short8v*)(WOb + (size_t)((dt0 + u) * 16 + c) * 512 + ks * 32 + g * 8);
            acc[u] = __builtin_amdgcn_mfma_f32_16x16x32_bf16(a, b, acc[u], 0, 0, 0);
        }
    }
    #pragma unroll
    for (int u = 0; u < 2; ++u) {
        int d = (dt0 + u) * 16 + c;
        float bias = bO[d];
        #pragma unroll
        for (int m = 0; m < 4; ++m)
            out[(size_t)(mt * 16 + g * 4 + m) * 512 + d] = acc[u][m] + bias;
    }
}

extern "C" void kernel_launch(void* const* d_in, const int* in_sizes, int n_in,
                              void* d_out, int out_size, void* d_ws, size_t ws_size,
                              hipStream_t stream) {
    const float* x    = (const float*)d_in[0];
    const float* W_K1 = (const float*)d_in[1];
    const float* W_K2 = (const float*)d_in[2];
    const float* W_Q  = (const float*)d_in[3];
    const float* W_V1 = (const float*)d_in[4];
    const float* W_V2 = (const float*)d_in[5];
    const float* W_Kq = (const float*)d_in[6];
    const float* W_Vq = (const float*)d_in[7];
    const float* W_O  = (const float*)d_in[8];
    const float* b_K1 = (const float*)d_in[9];
    const float* b_K2 = (const float*)d_in[10];
    const float* b_Q  = (const float*)d_in[11];
    const float* b_V1 = (const float*)d_in[12];
    const float* b_V2 = (const float*)d_in[13];
    const float* b_O  = (const float*)d_in[14];
    float* ws = (float*)d_ws;
    short* sb = (short*)(ws + F_END);
    float* out = (float*)d_out;

    // converts
    cvt_kernel<<<64, 256, 0, stream>>>(x, sb + S_XB, 16384);
    cvt_kernel<<<1024, 256, 0, stream>>>(W_Kq, sb + S_KQB, 262144);
    wconv_kernel<<<40, 256, 0, stream>>>(W_K1, W_K2, W_Q, W_V1, W_V2, sb + S_WB);
    vqconv_kernel<<<512, 256, 0, stream>>>(W_Vq, sb + S_VQB);
    woconv_kernel<<<32, 256, 0, stream>>>(W_O, sb + S_WOB);

    // projections (bf16)
    proj_kernel<<<dim3(5, 8, 2), 512, 0, stream>>>(sb + S_XB, sb + S_WB,
                                                   b_K1, b_K2, b_Q, b_V1, b_V2, sb + S_PB);

    // step1[n][r][ij] and Ab[n][t][hi]
    bgemm_kernel<<<dim3(16, 8, 4), 256, 0, stream>>>(sb + S_PB + 2 * PROJ, sb + S_KQB, sb + S_S1B);
    bgemm_kernel<<<dim3(16, 8, 4), 256, 0, stream>>>(sb + S_PB + 4 * PROJ, sb + S_VQB, sb + S_AB);

    // G in [n][t][r][i], causal tiles only
    gmat_kernel<<<dim3(256, 8), 256, 0, stream>>>(sb + S_S1B, sb + S_PB + 1 * PROJ, sb + S_GB);

    hipMemsetAsync(ws + F_NUM, 0, (size_t)F_END * sizeof(float), stream);

    attn_kernel<<<dim3(32, 8), 512, 0, stream>>>(sb + S_PB, sb + S_PB + 3 * PROJ,
                                                 sb + S_GB, sb + S_AB,
                                                 ws + F_NUM, ws + F_DEN);

    zdiv_kernel<<<512, 256, 0, stream>>>(ws + F_NUM, ws + F_DEN, sb + S_ZB);
    out_kernel<<<32, 512, 0, stream>>>(sb + S_ZB, sb + S_WOB, b_O, out);
}

// Round 5
// 146.460 us; speedup vs baseline: 6.6369x; 1.1621x over previous
//
#include <hip/hip_runtime.h>
#include <hip/hip_bf16.h>
#include <math.h>

#define TT 256   // seq len
#define DD 512   // d_model
#define NN 8     // heads
#define HH 64    // head dim
#define PROJ 131072

typedef __attribute__((ext_vector_type(8))) short short8v;   // 8 bf16
typedef __attribute__((ext_vector_type(4))) short short4v;   // 4 bf16
typedef __attribute__((ext_vector_type(4))) float f32x4;

__device__ __forceinline__ short f2bf(float x) {
    union { float f; unsigned u; } v; v.f = x;
    unsigned r = (v.u + 0x7FFFu + ((v.u >> 16) & 1u)) >> 16;   // RNE
    return (short)r;
}

#define LGKM0 asm volatile("s_waitcnt lgkmcnt(0)" ::: "memory")

// ---------------- workspace layout ----------------
// float region (floats)
#define F_NUM  0            // 131072
#define F_DEN  131072       // 2048
#define F_END  133120
// short region, base = (short*)(ws + F_END), offsets in shorts
#define S_PB   0            // 5*131072  (K1,K2,Q,V1,V2 bf16 [p][n][t][h])
#define S_XB   655360       // 131072    xb[t][d]
#define S_WB   786432       // 1310720   Wb[p][n][h][d]
#define S_KQB  2097152      // 2097152   Kqb[n][ij][k]
#define S_VQB  4194304      // 2097152   Vqb[n][h][i][j]
#define S_WOB  6291456      // 262144    WOb[d][nh]
#define S_S1B  6553600      // 8388608   S1b[n][r][ij]
#define S_AB   14942208     // 8388608   Ab[n][t][h*64+i]
#define S_GB   23330816     // 33554432  G[n][t][r][i]   (t-major)

// =============== prep: all converts + num/den zeroing in ONE dispatch =========
// blocks: [0,1024) Kq cvt | [1024,1088) x cvt | [1088,1128) wconv |
//         [1128,1640) vqconv | [1640,1672) woconv | [1672,1802) zero num/den
__global__ __launch_bounds__(256) void prep_kernel(
    const float* __restrict__ x, const float* __restrict__ W_Kq,
    const float* __restrict__ W0, const float* __restrict__ W1,
    const float* __restrict__ W2, const float* __restrict__ W3,
    const float* __restrict__ W4, const float* __restrict__ Vq,
    const float* __restrict__ WO, short* __restrict__ sb, float* __restrict__ fz)
{
    __shared__ float plds[64 * 129];
    int b = blockIdx.x;
    int tid = threadIdx.x;
    if (b < 1024) {                       // cvt W_Kq -> Kqb (natural layout)
        int i = b * 256 + tid;
        const float4 f0 = *(const float4*)(W_Kq + (size_t)i * 8);
        const float4 f1 = *(const float4*)(W_Kq + (size_t)i * 8 + 4);
        short8v o;
        o[0]=f2bf(f0.x); o[1]=f2bf(f0.y); o[2]=f2bf(f0.z); o[3]=f2bf(f0.w);
        o[4]=f2bf(f1.x); o[5]=f2bf(f1.y); o[6]=f2bf(f1.z); o[7]=f2bf(f1.w);
        *(short8v*)(sb + S_KQB + (size_t)i * 8) = o;
    } else if (b < 1088) {                // cvt x -> xb
        int i = (b - 1024) * 256 + tid;
        const float4 f0 = *(const float4*)(x + (size_t)i * 8);
        const float4 f1 = *(const float4*)(x + (size_t)i * 8 + 4);
        short8v o;
        o[0]=f2bf(f0.x); o[1]=f2bf(f0.y); o[2]=f2bf(f0.z); o[3]=f2bf(f0.w);
        o[4]=f2bf(f1.x); o[5]=f2bf(f1.y); o[6]=f2bf(f1.z); o[7]=f2bf(f1.w);
        *(short8v*)(sb + S_XB + (size_t)i * 8) = o;
    } else if (b < 1128) {                // Wb[p][n][h][d] <- W_p[n][d][h]
        int pn = b - 1088; int p = pn >> 3, n = pn & 7;
        const float* Wp = (p==0)?W0:(p==1)?W1:(p==2)?W2:(p==3)?W3:W4;
        const float* src = Wp + (size_t)n * DD * HH;
        short* dst = sb + S_WB + (size_t)pn * HH * DD;
        for (int d0 = 0; d0 < DD; d0 += 64) {
            __syncthreads();
            for (int it = 0; it < 16; ++it) {
                int m = it * 256 + tid;
                int dl = m >> 6, h = m & 63;
                plds[h * 65 + dl] = src[(size_t)(d0 + dl) * 64 + h];
            }
            __syncthreads();
            int h = tid >> 2, seg = tid & 3;
            short8v o0, o1;
            #pragma unroll
            for (int e = 0; e < 8; ++e) o0[e] = f2bf(plds[h * 65 + seg * 16 + e]);
            #pragma unroll
            for (int e = 0; e < 8; ++e) o1[e] = f2bf(plds[h * 65 + seg * 16 + 8 + e]);
            *(short8v*)(dst + (size_t)h * DD + d0 + seg * 16) = o0;
            *(short8v*)(dst + (size_t)h * DD + d0 + seg * 16 + 8) = o1;
        }
    } else if (b < 1640) {                // Vqb[n][h][i][j] <- W_Vq[n][i][j][h]
        int bb = b - 1128; int n = bb >> 6, i = bb & 63;
        const float* src = Vq + (size_t)(n * 64 + i) * 4096;
        for (int it = 0; it < 16; ++it) {
            int m = it * 256 + tid;
            int j = m >> 6, h = m & 63;
            plds[h * 65 + j] = src[(size_t)j * 64 + h];
        }
        __syncthreads();
        int h = tid >> 2, seg = tid & 3;
        short8v o0, o1;
        #pragma unroll
        for (int e = 0; e < 8; ++e) o0[e] = f2bf(plds[h * 65 + seg * 16 + e]);
        #pragma unroll
        for (int e = 0; e < 8; ++e) o1[e] = f2bf(plds[h * 65 + seg * 16 + 8 + e]);
        short* dst = sb + S_VQB + (size_t)n * 262144 + (size_t)h * 4096 + i * 64 + seg * 16;
        *(short8v*)dst = o0;
        *(short8v*)(dst + 8) = o1;
    } else if (b < 1672) {                // WOb[d][nh] <- W_O[nh][d]
        int bb = b - 1640; int dc = bb & 7, nhc = bb >> 3;
        for (int it = 0; it < 32; ++it) {
            int m = it * 256 + tid;
            int nhl = m >> 6, dl = m & 63;
            plds[dl * 129 + nhl] = WO[(size_t)(nhc * 128 + nhl) * 512 + dc * 64 + dl];
        }
        __syncthreads();
        for (int it = 0; it < 4; ++it) {
            int m = it * 256 + tid;
            int dl = m >> 4, seg = m & 15;
            short8v o;
            #pragma unroll
            for (int e = 0; e < 8; ++e) o[e] = f2bf(plds[dl * 129 + seg * 8 + e]);
            *(short8v*)(sb + S_WOB + (size_t)(dc * 64 + dl) * 512 + nhc * 128 + seg * 8) = o;
        }
    } else {                              // zero num+den (130 blocks x 1024 floats)
        int i = (b - 1672) * 1024 + tid * 4;
        *(float4*)(fz + i) = make_float4(0.f, 0.f, 0.f, 0.f);
    }
}

// ---------------- proj (MFMA): Pb[p][n][t][h] = xb[t][:] . Wb[p][n][h][:] + b --
__global__ __launch_bounds__(512) void proj_kernel(
    const short* __restrict__ xb, const short* __restrict__ Wb,
    const float* __restrict__ bK1, const float* __restrict__ bK2,
    const float* __restrict__ bQ,  const float* __restrict__ bV1,
    const float* __restrict__ bV2, short* __restrict__ Pb) {
    int p = blockIdx.x, n = blockIdx.y, mhalf = blockIdx.z;
    int wv = threadIdx.x >> 6, lane = threadIdx.x & 63, g = lane >> 4, c = lane & 15;
    __shared__ short wlds[64 * 520];
    __shared__ short sbuf[8][16 * 72];
    const short* wsrc = Wb + (size_t)(p * 8 + n) * HH * DD;
    for (int it = 0; it < 8; ++it) {
        int idx = it * 512 + threadIdx.x;
        int h = idx >> 6, seg = idx & 63;
        *(short8v*)(&wlds[h * 520 + seg * 8]) = *(const short8v*)(wsrc + (size_t)h * DD + seg * 8);
    }
    __syncthreads();
    int mt = mhalf * 8 + wv;
    f32x4 acc[4];
    #pragma unroll
    for (int ct = 0; ct < 4; ++ct) acc[ct] = (f32x4){0.f, 0.f, 0.f, 0.f};
    for (int ks = 0; ks < 16; ++ks) {
        short8v a = *(const short8v*)(xb + (size_t)(mt * 16 + c) * DD + ks * 32 + g * 8);
        #pragma unroll
        for (int ct = 0; ct < 4; ++ct) {
            short8v b = *(const short8v*)(&wlds[(ct * 16 + c) * 520 + ks * 32 + g * 8]);
            acc[ct] = __builtin_amdgcn_mfma_f32_16x16x32_bf16(a, b, acc[ct], 0, 0, 0);
        }
    }
    const float* bp = (p == 0) ? bK1 : (p == 1) ? bK2 : (p == 2) ? bQ : (p == 3) ? bV1 : bV2;
    short* sbw = &sbuf[wv][0];
    #pragma unroll
    for (int ct = 0; ct < 4; ++ct) {
        float bias = bp[n * 64 + ct * 16 + c];
        #pragma unroll
        for (int m = 0; m < 4; ++m)
            sbw[(g * 4 + m) * 72 + ct * 16 + c] = f2bf(acc[ct][m] + bias);
    }
    LGKM0;
    int rl = lane & 15, sg = lane >> 4;
    short8v o0 = *(const short8v*)(&sbw[rl * 72 + sg * 16]);
    short8v o1 = *(const short8v*)(&sbw[rl * 72 + sg * 16 + 8]);
    short* dst = Pb + (size_t)p * PROJ + (size_t)(n * 256 + mt * 16 + rl) * 64 + sg * 16;
    *(short8v*)dst = o0;
    *(short8v*)(dst + 8) = o1;
}

// ------ merged batch GEMM: z<4 -> step1 (A0,B0,O0), z>=4 -> Ab (A1,B1,O1) ------
__global__ __launch_bounds__(256) void bgemm_kernel(
    const short* __restrict__ A0, const short* __restrict__ B0, short* __restrict__ O0,
    const short* __restrict__ A1, const short* __restrict__ B1, short* __restrict__ O1) {
    int mt = blockIdx.x, n = blockIdx.y, z = blockIdx.z;
    const short* A = (z < 4) ? A0 : A1;
    const short* B = (z < 4) ? B0 : B1;
    short* out = (z < 4) ? O0 : O1;
    int cgq = z & 3;
    int wv = threadIdx.x >> 6, lane = threadIdx.x & 63, g = lane >> 4, c = lane & 15;
    __shared__ short sbuf[4][16 * 72];
    short* sbw = &sbuf[wv][0];
    const short* abase = A + ((size_t)n * 256 + mt * 16 + c) * 64 + g * 8;
    short8v a0 = *(const short8v*)abase;
    short8v a1 = *(const short8v*)(abase + 32);
    for (int cg = cgq * 16 + wv; cg < cgq * 16 + 16; cg += 4) {
        f32x4 acc[4];
        #pragma unroll
        for (int jt = 0; jt < 4; ++jt) acc[jt] = (f32x4){0.f, 0.f, 0.f, 0.f};
        const short* bb = B + ((size_t)n * 4096 + cg * 64) * 64;
        #pragma unroll
        for (int jt = 0; jt < 4; ++jt) {
            short8v b0 = *(const short8v*)(bb + (size_t)(jt * 16 + c) * 64 + g * 8);
            short8v b1 = *(const short8v*)(bb + (size_t)(jt * 16 + c) * 64 + g * 8 + 32);
            acc[jt] = __builtin_amdgcn_mfma_f32_16x16x32_bf16(a0, b0, acc[jt], 0, 0, 0);
            acc[jt] = __builtin_amdgcn_mfma_f32_16x16x32_bf16(a1, b1, acc[jt], 0, 0, 0);
        }
        LGKM0;
        #pragma unroll
        for (int jt = 0; jt < 4; ++jt)
            #pragma unroll
            for (int m = 0; m < 4; ++m)
                sbw[(g * 4 + m) * 72 + jt * 16 + c] = f2bf(acc[jt][m]);
        LGKM0;
        int rl = lane & 15, sg = lane >> 4;
        short8v o0 = *(const short8v*)(&sbw[rl * 72 + sg * 16]);
        short8v o1 = *(const short8v*)(&sbw[rl * 72 + sg * 16 + 8]);
        short* dst = out + ((size_t)n * 256 + mt * 16 + rl) * 4096 + cg * 64 + sg * 16;
        *(short8v*)dst = o0;
        *(short8v*)(dst + 8) = o1;
    }
}

// ---------- G[n][t][r][i] = sum_j S1[n][r][i][j]*k2[n][t][j]  (coalesced) ------
// flat grid 512: n=bid&7 (XCD affinity), tt=(bid>>3)&15, rq=bid>>7.
// wave wv: r = t0 + rq*4 + wv, stride 16. Epilogue: wave-local LDS transpose,
// stores 128B contiguous per (t,r) row.
__global__ __launch_bounds__(256) void gmat_kernel(const short* __restrict__ S1b,
                                                   const short* __restrict__ K2b,
                                                   short* __restrict__ G) {
    int bid = blockIdx.x;
    int n = bid & 7;
    int tt = (bid >> 3) & 15;
    int rq = bid >> 7;
    int wv = threadIdx.x >> 6, lane = threadIdx.x & 63, g = lane >> 4, c = lane & 15;
    int t0 = tt * 16;
    __shared__ short sbuf[4][16 * 68];
    short* sbw = &sbuf[wv][0];
    const short* abase = K2b + ((size_t)n * TT + t0 + c) * 64 + g * 8;
    short8v a0 = *(const short8v*)abase;
    short8v a1 = *(const short8v*)(abase + 32);
    for (int r = t0 + rq * 4 + wv; r < 256; r += 16) {
        const short* bb = S1b + ((size_t)(n * 256 + r) * 64) * 64;
        f32x4 acc[4];
        #pragma unroll
        for (int it = 0; it < 4; ++it) {
            short8v b0 = *(const short8v*)(bb + (size_t)(it * 16 + c) * 64 + g * 8);
            short8v b1 = *(const short8v*)(bb + (size_t)(it * 16 + c) * 64 + g * 8 + 32);
            acc[it] = (f32x4){0.f, 0.f, 0.f, 0.f};
            acc[it] = __builtin_amdgcn_mfma_f32_16x16x32_bf16(a0, b0, acc[it], 0, 0, 0);
            acc[it] = __builtin_amdgcn_mfma_f32_16x16x32_bf16(a1, b1, acc[it], 0, 0, 0);
        }
        LGKM0;   // previous iteration's sbuf reads complete
        #pragma unroll
        for (int it = 0; it < 4; ++it)
            #pragma unroll
            for (int m = 0; m < 4; ++m)
                sbw[(g * 4 + m) * 68 + it * 16 + c] = f2bf(acc[it][m]);
        LGKM0;
        int trow = lane >> 2, seg = (lane & 3) * 16;
        short8v o0 = *(const short8v*)(&sbw[trow * 68 + seg]);
        short8v o1 = *(const short8v*)(&sbw[trow * 68 + seg + 8]);
        short* dst = G + (((size_t)(n * TT + t0 + trow)) * TT + r) * 64 + seg;
        *(short8v*)dst = o0;
        *(short8v*)(dst + 8) = o1;
    }
}

// ---------- fused cubic attention: flat grid 512, 1024 threads ----------------
// n=bid&7 (XCD affinity), pair=(bid>>3)>>2, sig=(bid>>3)&3.
// 16 waves, wave wv owns rt-tile wv. One barrier per t (double-buffered u_lds).
__global__ __launch_bounds__(1024) void attn_kernel(
    const short* __restrict__ K1b, const short* __restrict__ V1b,
    const short* __restrict__ Gm, const short* __restrict__ Ab,
    float* __restrict__ num, float* __restrict__ den)
{
    int bid = blockIdx.x;
    int n = bid & 7;
    int rest = bid >> 3;          // 0..63
    int pair = rest >> 2;         // 0..15
    int sig = rest & 3;           // 0..3
    int tid = threadIdx.x;
    int wv = tid >> 6, lane = tid & 63, g = lane >> 4, c = lane & 15;

    __shared__ short k1lds[64 * 72];
    __shared__ short v1lds[64 * 72];
    __shared__ short u_lds[2][64 * 68];

    int t0H = (31 - pair) * 8;
    int stmaxK = (t0H + 6) >> 4;
    int cntK = (stmaxK >= sig) ? ((stmaxK - sig) >> 2) + 1 : 0;   // <= 4
    for (int idx = tid; idx < cntK * 128; idx += 1024) {
        int row = idx >> 3, seg = idx & 7;
        int s = (sig + (row >> 4) * 4) * 16 + (row & 15);
        *(short8v*)(&k1lds[row * 72 + seg * 8]) =
            *(const short8v*)(K1b + ((size_t)n * TT + s) * 64 + seg * 8);
        *(short8v*)(&v1lds[row * 72 + seg * 8]) =
            *(const short8v*)(V1b + ((size_t)n * TT + s) * 64 + seg * 8);
    }
    __syncthreads();

    f32x4 numacc[4];
    #pragma unroll
    for (int b = 0; b < 4; ++b) numacc[b] = (f32x4){0.f, 0.f, 0.f, 0.f};
    float denacc = 0.f;
    int rt = wv;                  // 0..15
    int ubuf = 0;

    for (int part = 0; part < 2; ++part) {
        int t0 = part ? t0H : pair * 8;
        for (int th = 0; th < 8; ++th) {
            int t = t0 + th;
            if (t < 1 || t > 254) continue;
            int rt_start = (t + 1) >> 4;
            int stmaxU = (t - 1) >> 4;
            int cntU = (stmaxU >= sig) ? ((stmaxU - sig) >> 2) + 1 : 0;   // <= 4
            if (cntU == 0) continue;

            bool valid = (rt >= rt_start);
            short8v gf0, gf1;
            if (valid) {   // issue early: overlaps U phase
                const short* gb = Gm + (((size_t)(n * TT + t) * TT) + rt * 16 + c) * 64 + g * 8;
                gf0 = *(const short8v*)gb;
                gf1 = *(const short8v*)(gb + 32);
            }

            short* uw = &u_lds[ubuf][0];
            // cooperative U: one task per wave (cntU*4 <= 16 tasks)
            if (wv < cntU * 4) {
                int loc = wv >> 2, hs = wv & 3;
                const short* vr = &v1lds[(loc * 16 + c) * 72 + g * 8];
                short8v vf0 = *(const short8v*)vr;
                short8v vf1 = *(const short8v*)(vr + 32);
                const short* ar = Ab + (size_t)(n * TT + t) * 4096 + (hs * 16 + c) * 64 + g * 8;
                short8v ab0 = *(const short8v*)ar;
                short8v ab1 = *(const short8v*)(ar + 32);
                f32x4 ucc = (f32x4){0.f, 0.f, 0.f, 0.f};
                ucc = __builtin_amdgcn_mfma_f32_16x16x32_bf16(vf0, ab0, ucc, 0, 0, 0);
                ucc = __builtin_amdgcn_mfma_f32_16x16x32_bf16(vf1, ab1, ucc, 0, 0, 0);
                short4v uo;
                #pragma unroll
                for (int m = 0; m < 4; ++m) uo[m] = f2bf(ucc[m]);
                *(short4v*)(&uw[(hs * 16 + c) * 68 + loc * 16 + g * 4]) = uo;
            }
            __syncthreads();
            ubuf ^= 1;

            if (valid) {
                int r = rt * 16 + c;
                for (int loc = 0; loc < cntU; ++loc) {
                    int s_base = (sig + loc * 4) * 16;
                    const short* kr = &k1lds[(loc * 16 + c) * 72 + g * 8];
                    short8v af0 = *(const short8v*)kr;
                    short8v af1 = *(const short8v*)(kr + 32);
                    f32x4 lg = (f32x4){0.f, 0.f, 0.f, 0.f};
                    lg = __builtin_amdgcn_mfma_f32_16x16x32_bf16(af0, gf0, lg, 0, 0, 0);
                    lg = __builtin_amdgcn_mfma_f32_16x16x32_bf16(af1, gf1, lg, 0, 0, 0);
                    short4v eb;
                    float dsum = 0.f;
                    #pragma unroll
                    for (int m = 0; m < 4; ++m) {
                        int s = s_base + g * 4 + m;
                        float e = (s < t && r > t) ? __expf(lg[m] * 0.015625f) : 0.f;
                        dsum += e;
                        eb[m] = f2bf(e);
                    }
                    denacc += dsum;
                    #pragma unroll
                    for (int hs = 0; hs < 4; ++hs) {
                        short4v ub = *(const short4v*)(&uw[(hs * 16 + c) * 68 + loc * 16 + g * 4]);
                        numacc[hs] = __builtin_amdgcn_mfma_f32_16x16x16bf16_1k(eb, ub, numacc[hs], 0, 0, 0);
                    }
                }
            }
        }
    }

    // epilogue: skip entirely if this wave never produced a contribution
    if (__any(denacc != 0.f)) {
        float v = denacc;
        v += __shfl_xor(v, 16);
        v += __shfl_xor(v, 32);
        if (lane < 16) atomicAdd(&den[n * TT + rt * 16 + lane], v);
        #pragma unroll
        for (int hs = 0; hs < 4; ++hs)
            #pragma unroll
            for (int m = 0; m < 4; ++m)
                atomicAdd(&num[((size_t)(n * TT + rt * 16 + g * 4 + m)) * 64 + hs * 16 + c],
                          numacc[hs][m]);
    }
}

// ---------- out[t][d] = b_O[d] + (num/den)[t][:] . WOb[d][:]  (fused zdiv) -----
__global__ __launch_bounds__(512) void out_kernel(const float* __restrict__ num,
                                                  const float* __restrict__ den,
                                                  const short* __restrict__ WOb,
                                                  const float* __restrict__ bO,
                                                  float* __restrict__ out) {
    int mt = blockIdx.x & 15, dq = blockIdx.x >> 4;
    int wv = threadIdx.x >> 6, lane = threadIdx.x & 63, g = lane >> 4, c = lane & 15;
    int dt0 = dq * 16 + wv * 2;
    int t = mt * 16 + c;
    f32x4 acc[2];
    acc[0] = (f32x4){0.f, 0.f, 0.f, 0.f};
    acc[1] = (f32x4){0.f, 0.f, 0.f, 0.f};
    for (int ks = 0; ks < 16; ++ks) {
        int nh = ks * 32 + g * 8;
        int nn = nh >> 6, h = nh & 63;
        float dv = den[nn * 256 + t];
        float rcp = (dv > 0.f) ? 1.f / dv : 0.f;
        const float* np = num + ((size_t)(nn * 256 + t) * 64 + h);
        float4 f0 = *(const float4*)np;
        float4 f1 = *(const float4*)(np + 4);
        short8v a;
        a[0]=f2bf(f0.x*rcp); a[1]=f2bf(f0.y*rcp); a[2]=f2bf(f0.z*rcp); a[3]=f2bf(f0.w*rcp);
        a[4]=f2bf(f1.x*rcp); a[5]=f2bf(f1.y*rcp); a[6]=f2bf(f1.z*rcp); a[7]=f2bf(f1.w*rcp);
        #pragma unroll
        for (int u = 0; u < 2; ++u) {
            short8v b = *(const short8v*)(WOb + (size_t)((dt0 + u) * 16 + c) * 512 + ks * 32 + g * 8);
            acc[u] = __builtin_amdgcn_mfma_f32_16x16x32_bf16(a, b, acc[u], 0, 0, 0);
        }
    }
    #pragma unroll
    for (int u = 0; u < 2; ++u) {
        int d = (dt0 + u) * 16 + c;
        float bias = bO[d];
        #pragma unroll
        for (int m = 0; m < 4; ++m)
            out[(size_t)(mt * 16 + g * 4 + m) * 512 + d] = acc[u][m] + bias;
    }
}

extern "C" void kernel_launch(void* const* d_in, const int* in_sizes, int n_in,
                              void* d_out, int out_size, void* d_ws, size_t ws_size,
                              hipStream_t stream) {
    const float* x    = (const float*)d_in[0];
    const float* W_K1 = (const float*)d_in[1];
    const float* W_K2 = (const float*)d_in[2];
    const float* W_Q  = (const float*)d_in[3];
    const float* W_V1 = (const float*)d_in[4];
    const float* W_V2 = (const float*)d_in[5];
    const float* W_Kq = (const float*)d_in[6];
    const float* W_Vq = (const float*)d_in[7];
    const float* W_O  = (const float*)d_in[8];
    const float* b_K1 = (const float*)d_in[9];
    const float* b_K2 = (const float*)d_in[10];
    const float* b_Q  = (const float*)d_in[11];
    const float* b_V1 = (const float*)d_in[12];
    const float* b_V2 = (const float*)d_in[13];
    const float* b_O  = (const float*)d_in[14];
    float* ws = (float*)d_ws;
    short* sb = (short*)(ws + F_END);
    float* out = (float*)d_out;

    // all converts + num/den zeroing
    prep_kernel<<<1802, 256, 0, stream>>>(x, W_Kq, W_K1, W_K2, W_Q, W_V1, W_V2,
                                          W_Vq, W_O, sb, ws + F_NUM);

    // projections (bf16)
    proj_kernel<<<dim3(5, 8, 2), 512, 0, stream>>>(sb + S_XB, sb + S_WB,
                                                   b_K1, b_K2, b_Q, b_V1, b_V2, sb + S_PB);

    // step1[n][r][ij] and Ab[n][t][hi] in one dispatch
    bgemm_kernel<<<dim3(16, 8, 8), 256, 0, stream>>>(
        sb + S_PB + 2 * PROJ, sb + S_KQB, sb + S_S1B,
        sb + S_PB + 4 * PROJ, sb + S_VQB, sb + S_AB);

    // G in [n][t][r][i], coalesced stores
    gmat_kernel<<<512, 256, 0, stream>>>(sb + S_S1B, sb + S_PB + 1 * PROJ, sb + S_GB);

    // fused cubic attention
    attn_kernel<<<512, 1024, 0, stream>>>(sb + S_PB, sb + S_PB + 3 * PROJ,
                                          sb + S_GB, sb + S_AB,
                                          ws + F_NUM, ws + F_DEN);

    // output projection with fused zdiv
    out_kernel<<<32, 512, 0, stream>>>(ws + F_NUM, ws + F_DEN, sb + S_WOB, b_O, out);
}